// Round 5
// baseline (2025.182 us; speedup 1.0000x reference)
//
#include <hip/hip_runtime.h>
#include <hip/hip_bf16.h>

using bf16 = __hip_bfloat16;
typedef __attribute__((ext_vector_type(4))) float f32x4;
typedef __attribute__((ext_vector_type(8))) short s16x8;

#define DEV static __device__ __forceinline__
DEV float bf2f(bf16 x){ return __bfloat162float(x); }
DEV bf16  f2bf(float x){ return __float2bfloat16(x); }
DEV float silu_(float x){ return x / (1.f + expf(-x)); }

// ------------------------------------------------------------------
// Common pipelined bf16 MFMA GEMM core:  C = alpha * (A @ B^T) (+ bias)
// A bf16 rows (lda=K). B f32 or bf16 rows (ldb=K).
// EXPERT: Meff=counts[z], rowbase=offsets[z]; GATHER: A row via rowlist.
// OUT: 0 = f32 store, 1 = bf16 store. EPI: v = silu(G[cidx]) * v before store.
// ksplit: blockIdx.z = z*ksplit + split; K-range [split*K/ksplit ...);
// split s writes at +s*c_spo (disjoint buffers, summed later by consumer).
// ------------------------------------------------------------------
template<bool B_F32, bool EXPERT, bool GATHER, int OUT, bool BIAS, bool EPI>
DEV void gemm_core(
    const bf16* __restrict__ A, const bf16* __restrict__ G,
    const void* __restrict__ Bv,
    const float* __restrict__ bias, void* __restrict__ C,
    int M, int N, int K, long a_zoff, long b_zoff,
    int zdiv, long c_so, long c_si, int ldc,
    float alpha, int ksplit, long c_spo,
    const int* __restrict__ rowlist, const int* __restrict__ offsets,
    const int* __restrict__ counts)
{
  __shared__ __align__(16) bf16 As[128][72];
  __shared__ __align__(16) bf16 Bs[128][72];
  const int zz = blockIdx.z;
  const int z = zz / ksplit, split = zz % ksplit;
  const int m0 = blockIdx.y * 128, n0 = blockIdx.x * 128;
  int Meff = M; long rowbase = 0;
  if (EXPERT){ Meff = counts[z]; rowbase = offsets[z]; }
  if (m0 >= Meff) return;
  const bf16* Ab = A + (EXPERT ? 0 : z * a_zoff);
  long coff;
  if (EXPERT) coff = rowbase * (long)ldc;
  else        coff = (long)(z / zdiv) * c_so + (long)(z % zdiv) * c_si;

  const int klen = K / ksplit;
  const int kbeg = split * klen;
  const int NT = klen >> 6;

  const int tid = threadIdx.x;
  const int lane = tid & 63, wid = tid >> 6;
  const int wm = wid >> 1, wn = wid & 1;

  const int rbase = tid >> 3;
  const int kc = (tid & 7) << 3;
  const bf16* ap[4];
  const bf16* bp[4]; const float* bpf[4];
  bool avalid[4], bvalid[4];
  #pragma unroll
  for (int it = 0; it < 4; it++){
    int row = rbase + 32 * it;
    long ar = 0;
    if (EXPERT){
      int i = m0 + row;
      avalid[it] = i < Meff;
      if (avalid[it]) ar = GATHER ? (long)rowlist[rowbase + i] : (rowbase + i);
    } else {
      avalid[it] = (m0 + row) < Meff;
      ar = m0 + row;
    }
    ap[it] = Ab + ar * (long)K + kbeg + kc;
    bvalid[it] = (n0 + row) < N;
    long br = bvalid[it] ? (long)(n0 + row) : 0;
    if (B_F32) bpf[it] = (const float*)Bv + z * b_zoff + br * K + kbeg + kc;
    else       bp[it]  = (const bf16*) Bv + z * b_zoff + br * K + kbeg + kc;
  }

  uint4 ra[4], rb[4];
  float4 fb0[4], fb1[4];
  const uint4 zero4 = make_uint4(0u,0u,0u,0u);

  auto LOAD = [&](int koff){
    #pragma unroll
    for (int it = 0; it < 4; it++){
      ra[it] = avalid[it] ? *(const uint4*)(ap[it] + koff) : zero4;
      if (B_F32){
        if (bvalid[it]){ fb0[it] = *(const float4*)(bpf[it] + koff);
                         fb1[it] = *(const float4*)(bpf[it] + koff + 4); }
        else { fb0[it] = make_float4(0,0,0,0); fb1[it] = make_float4(0,0,0,0); }
      } else {
        rb[it] = bvalid[it] ? *(const uint4*)(bp[it] + koff) : zero4;
      }
    }
  };
  auto STORE = [&](){
    #pragma unroll
    for (int it = 0; it < 4; it++){
      int row = rbase + 32 * it;
      *(uint4*)(&As[row][kc]) = ra[it];
      if (B_F32){
        union { bf16 h[8]; uint4 v; } u;
        u.h[0]=f2bf(fb0[it].x); u.h[1]=f2bf(fb0[it].y); u.h[2]=f2bf(fb0[it].z); u.h[3]=f2bf(fb0[it].w);
        u.h[4]=f2bf(fb1[it].x); u.h[5]=f2bf(fb1[it].y); u.h[6]=f2bf(fb1[it].z); u.h[7]=f2bf(fb1[it].w);
        *(uint4*)(&Bs[row][kc]) = u.v;
      } else {
        *(uint4*)(&Bs[row][kc]) = rb[it];
      }
    }
  };

  f32x4 acc[4][4] = {};
  LOAD(0);
  for (int t = 0; t < NT; t++){
    STORE();
    __syncthreads();
    if (t + 1 < NT) LOAD((t + 1) << 6);
    #pragma unroll
    for (int ks = 0; ks < 2; ks++){
      const int r16 = lane & 15;
      const int kk = ks * 32 + ((lane >> 4) << 3);
      s16x8 af[4], bfr[4];
      #pragma unroll
      for (int mi = 0; mi < 4; mi++) af[mi]  = *(const s16x8*)(&As[wm*64 + mi*16 + r16][kk]);
      #pragma unroll
      for (int ni = 0; ni < 4; ni++) bfr[ni] = *(const s16x8*)(&Bs[wn*64 + ni*16 + r16][kk]);
      #pragma unroll
      for (int mi = 0; mi < 4; mi++)
        #pragma unroll
        for (int ni = 0; ni < 4; ni++)
          acc[mi][ni] = __builtin_amdgcn_mfma_f32_16x16x32_bf16(af[mi], bfr[ni], acc[mi][ni], 0, 0, 0);
    }
    __syncthreads();
  }
  #pragma unroll
  for (int mi = 0; mi < 4; mi++){
    #pragma unroll
    for (int ni = 0; ni < 4; ni++){
      int col = n0 + wn*64 + ni*16 + (lane & 15);
      if (col >= N) continue;
      float bv = 0.f;
      if (BIAS && split == 0) bv = bias[col];
      #pragma unroll
      for (int i = 0; i < 4; i++){
        int rr = m0 + wm*64 + mi*16 + ((lane >> 4) << 2) + i;
        if (rr >= Meff) continue;
        float v = acc[mi][ni][i] * alpha + bv;
        long cidx = coff + (long)rr * ldc + col + (long)split * c_spo;
        if (OUT == 1){
          if (EPI) v = silu_(bf2f(G[cidx])) * v;
          ((bf16*)C)[cidx] = f2bf(v);
        } else {
          ((float*)C)[cidx] = v;
        }
      }
    }
  }
}

#define GEMM_K(NAME, BF32, EXPERT, GATHER, OUT, BIAS, EPI)                         \
__global__ __launch_bounds__(256) void NAME(                                       \
    const bf16* A, const bf16* G, const void* Bv, const float* bias, void* C,      \
    int M, int N, int K, long az, long bz, int zdiv, long cso, long csi, int ldc,  \
    float alpha, int ks, long cspo, const int* rl, const int* ofs, const int* cnt){\
  gemm_core<BF32,EXPERT,GATHER,OUT,BIAS,EPI>(A,G,Bv,bias,C,M,N,K,az,bz,zdiv,cso,   \
      csi,ldc,alpha,ks,cspo,rl,ofs,cnt); }

// bf16-weight (tier A) variants — distinct names for rocprof attribution
GEMM_K(k_qkv_b,  false,false,false,1,true ,false)
GEMM_K(k_qkt,    false,false,false,1,false,false)
GEMM_K(k_pv,     false,false,false,1,false,false)
GEMM_K(k_proj_b, false,false,false,0,true ,false)
GEMM_K(k_gate_b, false,true ,true ,1,false,false)
GEMM_K(k_up_b,   false,true ,true ,1,false,true )
GEMM_K(k_down_b, false,true ,false,0,false,false)
GEMM_K(k_shg_b,  false,false,false,1,false,false)
GEMM_K(k_shu_b,  false,false,false,1,false,true )
GEMM_K(k_shd_b,  false,false,false,0,false,false)
// f32-weight (tier B fallback) variants
GEMM_K(k_qkv_f,  true ,false,false,1,true ,false)
GEMM_K(k_proj_f, true ,false,false,0,true ,false)
GEMM_K(k_gate_f, true ,true ,true ,1,false,false)
GEMM_K(k_up_f,   true ,true ,true ,1,false,true )
GEMM_K(k_down_f, true ,true ,false,0,false,false)
GEMM_K(k_shg_f,  true ,false,false,1,false,false)
GEMM_K(k_shu_f,  true ,false,false,1,false,true )
GEMM_K(k_shd_f,  true ,false,false,0,false,false)

using GemmFn = void(*)(const bf16*, const bf16*, const void*, const float*, void*,
                       int,int,int,long,long,int,long,long,int,float,int,long,
                       const int*, const int*, const int*);

// ---- f32 -> bf16 convert (n % 8 == 0) ------------------------------------------
__global__ __launch_bounds__(256) void f2b_kernel(const float* __restrict__ in,
    bf16* __restrict__ out, long n){
  long i = ((long)blockIdx.x * 256 + threadIdx.x) * 8;
  if (i >= n) return;
  float4 a = *(const float4*)(in + i);
  float4 b = *(const float4*)(in + i + 4);
  union { bf16 h[8]; uint4 v; } u;
  u.h[0]=f2bf(a.x); u.h[1]=f2bf(a.y); u.h[2]=f2bf(a.z); u.h[3]=f2bf(a.w);
  u.h[4]=f2bf(b.x); u.h[5]=f2bf(b.y); u.h[6]=f2bf(b.z); u.h[7]=f2bf(b.w);
  *(uint4*)(out + i) = u.v;
}

// ---- modulation GEMV (wave-per-output, coalesced) ------------------------------
__global__ __launch_bounds__(256) void mod_kernel(const float* __restrict__ vec,
    const float* __restrict__ w, const float* __restrict__ b, float* __restrict__ out){
  int bb = blockIdx.y;
  __shared__ float sv[768];
  int tid = threadIdx.x;
  for (int i = tid; i < 768; i += 256){ float v = vec[bb*768 + i]; sv[i] = v/(1.f+expf(-v)); }
  __syncthreads();
  int w4 = tid >> 6, lane = tid & 63;
  int j0 = blockIdx.x * 8 + w4 * 2;
  for (int jj = 0; jj < 2; jj++){
    int j = j0 + jj;
    const float* wr = w + (long)j * 768;
    float p = 0.f;
    #pragma unroll
    for (int i = 0; i < 12; i++) p += sv[lane + 64*i] * wr[lane + 64*i];
    for (int o = 32; o; o >>= 1) p += __shfl_xor(p, o);
    if (lane == 0) out[bb*4608 + j] = p + b[j];
  }
}

// ---------------- y = (1+c)*LN(x) + s  (bf16 out) --------------------------------
__global__ __launch_bounds__(256) void ln_mod_kernel(const float* __restrict__ x,
    const float* __restrict__ mod, int sOff, int cOff, bf16* __restrict__ y, int L){
  int t = blockIdx.x; int b = t / L;
  const float* xr = x + (long)t * 768;
  __shared__ float red[256];
  int tid = threadIdx.x;
  float v[3]; float s = 0.f;
  #pragma unroll
  for (int i = 0; i < 3; i++){ v[i] = xr[tid + 256*i]; s += v[i]; }
  red[tid] = s; __syncthreads();
  for (int o = 128; o; o >>= 1){ if (tid < o) red[tid] += red[tid+o]; __syncthreads(); }
  float mean = red[0] * (1.f/768.f); __syncthreads();
  float s2 = 0.f;
  #pragma unroll
  for (int i = 0; i < 3; i++){ float d = v[i]-mean; s2 += d*d; }
  red[tid] = s2; __syncthreads();
  for (int o = 128; o; o >>= 1){ if (tid < o) red[tid] += red[tid+o]; __syncthreads(); }
  float rs = rsqrtf(red[0] * (1.f/768.f) + 1e-6f);
  const float* mb = mod + (long)b * 4608;
  #pragma unroll
  for (int i = 0; i < 3; i++){
    int d = tid + 256*i;
    y[(long)t*768 + d] = f2bf((1.f + mb[cOff+d]) * ((v[i]-mean)*rs) + mb[sOff+d]);
  }
}

// ---- h = x + g1*proj ; y = (1+c2)*LN(h) + s2  (bf16 y + f32 yf) -----------------
__global__ __launch_bounds__(256) void resid_ln_mod_kernel(const float* __restrict__ x,
    const float* __restrict__ proj, const float* __restrict__ mod,
    float* __restrict__ h, bf16* __restrict__ y, float* __restrict__ yf, int L){
  int t = blockIdx.x; int b = t / L;
  const float* mb = mod + (long)b * 4608;
  const float* xr = x + (long)t * 768;
  const float* pr = proj + (long)t * 768;
  __shared__ float red[256];
  int tid = threadIdx.x;
  float v[3]; float s = 0.f;
  #pragma unroll
  for (int i = 0; i < 3; i++){
    int d = tid + 256*i;
    float hv = xr[d] + mb[2*768 + d] * pr[d];
    h[(long)t*768 + d] = hv;
    v[i] = hv; s += hv;
  }
  red[tid] = s; __syncthreads();
  for (int o = 128; o; o >>= 1){ if (tid < o) red[tid] += red[tid+o]; __syncthreads(); }
  float mean = red[0] * (1.f/768.f); __syncthreads();
  float s2 = 0.f;
  #pragma unroll
  for (int i = 0; i < 3; i++){ float d = v[i]-mean; s2 += d*d; }
  red[tid] = s2; __syncthreads();
  for (int o = 128; o; o >>= 1){ if (tid < o) red[tid] += red[tid+o]; __syncthreads(); }
  float rs = rsqrtf(red[0] * (1.f/768.f) + 1e-6f);
  #pragma unroll
  for (int i = 0; i < 3; i++){
    int d = tid + 256*i;
    float val = (1.f + mb[4*768+d]) * ((v[i]-mean)*rs) + mb[3*768+d];
    y[(long)t*768 + d] = f2bf(val);
    yf[(long)t*768 + d] = val;
  }
}

// ---- qkv rows -> RMS-normed Q,K + transposed V (coalesced via LDS) --------------
__global__ __launch_bounds__(256) void qkv_scatter_kernel(const bf16* __restrict__ qkv,
    const float* __restrict__ qs, const float* __restrict__ ks,
    bf16* __restrict__ Q, bf16* __restrict__ Kb, bf16* __restrict__ Vt,
    int L, int seqoff){
  __shared__ float vt[64][65];
  int bh = blockIdx.y;
  int b = bh / 12, hh = bh % 12;
  int st = blockIdx.x * 64;
  int w = threadIdx.x >> 6, lane = threadIdx.x & 63;
  float qsc = qs[lane], ksc = ks[lane];
  long qkvbase = (long)b * L * 2304;
  long outbase = (long)bh * 1280 * 64;
  #pragma unroll 4
  for (int i = 0; i < 16; i++){
    int r = w*16 + i;
    int t = st + r;
    const bf16* row = qkv + qkvbase + (long)t * 2304;
    float q = bf2f(row[hh*64 + lane]);
    float k = bf2f(row[768 + hh*64 + lane]);
    float v = bf2f(row[1536 + hh*64 + lane]);
    float q2 = q*q, k2 = k*k;
    for (int o = 32; o; o >>= 1){ q2 += __shfl_xor(q2, o); k2 += __shfl_xor(k2, o); }
    q = q * rsqrtf(q2*(1.f/64.f) + 1e-6f) * qsc;
    k = k * rsqrtf(k2*(1.f/64.f) + 1e-6f) * ksc;
    int seq = seqoff + t;
    Q [outbase + (long)seq*64 + lane] = f2bf(q);
    Kb[outbase + (long)seq*64 + lane] = f2bf(k);
    vt[r][lane] = v;
  }
  __syncthreads();
  #pragma unroll 4
  for (int i = 0; i < 16; i++){
    int d = w*16 + i;
    Vt[outbase + (long)d*1280 + seqoff + st + lane] = f2bf(vt[lane][d]);
  }
}

// ---- row softmax over 1280, bf16 in, bf16 out -----------------------------------
__global__ __launch_bounds__(256) void softmax_kernel(const bf16* __restrict__ S, bf16* __restrict__ P){
  long r = blockIdx.x;
  const bf16* sr = S + r * 1280;
  __shared__ float buf[1280];
  __shared__ float red[256];
  int tid = threadIdx.x;
  float mx = -1e30f;
  for (int i = tid; i < 1280; i += 256){ float v = bf2f(sr[i]); buf[i] = v; mx = fmaxf(mx, v); }
  red[tid] = mx; __syncthreads();
  for (int o = 128; o; o >>= 1){ if (tid < o) red[tid] = fmaxf(red[tid], red[tid+o]); __syncthreads(); }
  float m = red[0]; __syncthreads();
  float s = 0.f;
  for (int i = tid; i < 1280; i += 256){ float e = expf(buf[i] - m); buf[i] = e; s += e; }
  red[tid] = s; __syncthreads();
  for (int o = 128; o; o >>= 1){ if (tid < o) red[tid] += red[tid+o]; __syncthreads(); }
  float inv = 1.f / red[0];
  bf16* pr = P + r * 1280;
  for (int i = tid; i < 1280; i += 256) pr[i] = f2bf(buf[i] * inv);
}

// ---- router ---------------------------------------------------------------------
__global__ __launch_bounds__(256) void router_kernel(const float* __restrict__ x2,
    const float* __restrict__ gw, float* __restrict__ tkw, int* __restrict__ tki,
    int* __restrict__ counts, int T){
  int t = blockIdx.x * 4 + (threadIdx.x >> 6);
  int lane = threadIdx.x & 63;
  if (t >= T) return;
  const float* xr = x2 + (long)t * 768;
  float xs[12];
  #pragma unroll
  for (int i = 0; i < 12; i++) xs[i] = xr[lane + 64*i];
  float sc[8];
  #pragma unroll
  for (int e = 0; e < 8; e++){
    const float* gr = gw + e * 768;
    float p = 0.f;
    #pragma unroll
    for (int i = 0; i < 12; i++) p += xs[i] * gr[lane + 64*i];
    for (int o = 32; o; o >>= 1) p += __shfl_xor(p, o);
    sc[e] = p;
  }
  if (lane == 0){
    float m = sc[0];
    for (int e = 1; e < 8; e++) m = fmaxf(m, sc[e]);
    float s = 0.f;
    for (int e = 0; e < 8; e++){ sc[e] = expf(sc[e] - m); s += sc[e]; }
    float inv = 1.f / s;
    for (int e = 0; e < 8; e++) sc[e] *= inv;
    int i0 = 0;
    for (int e = 1; e < 8; e++) if (sc[e] > sc[i0]) i0 = e;
    int i1 = -1;
    for (int e = 0; e < 8; e++){ if (e == i0) continue; if (i1 < 0 || sc[e] > sc[i1]) i1 = e; }
    tkw[t*2] = sc[i0]; tkw[t*2+1] = sc[i1];
    tki[t*2] = i0;     tki[t*2+1] = i1;
    atomicAdd(&counts[i0], 1); atomicAdd(&counts[i1], 1);
  }
}

__global__ void zero_counts_kernel(int* a, int* b){
  int i = threadIdx.x; if (i < 8){ a[i] = 0; b[i] = 0; }
}

__global__ void offsets_kernel(const int* counts, int* offsets, int* cursor){
  if (threadIdx.x == 0){
    int o = 0;
    for (int e = 0; e < 8; e++){ offsets[e] = o; o += counts[e]; cursor[e] = 0; }
  }
}

__global__ __launch_bounds__(256) void scatter_kernel(const int* __restrict__ tki,
    const int* __restrict__ offsets, int* __restrict__ cursor,
    int* __restrict__ rows, int* __restrict__ tpos, int T){
  int idx = blockIdx.x * 256 + threadIdx.x;
  if (idx >= T * 2) return;
  int t = idx >> 1;
  int e = tki[idx];
  int pos = atomicAdd(&cursor[e], 1);
  int g = offsets[e] + pos;
  rows[g] = t;
  tpos[idx] = g;
}

// ---- out = h + g2 * (w0*(yeA+yeB)[p0] + w1*(yeA+yeB)[p1] + (ysA+ysB)) -----------
__global__ __launch_bounds__(256) void combine_kernel(const float* __restrict__ h,
    const float* __restrict__ mod, const float* __restrict__ tkw, const int* __restrict__ tpos,
    const float* __restrict__ ye, long espo, const float* __restrict__ ys, long sspo,
    float* __restrict__ out, int L){
  int t = blockIdx.x; int b = t / L;
  const float* g2 = mod + (long)b * 4608 + 5*768;
  float w0 = tkw[t*2], w1 = tkw[t*2+1];
  long p0 = (long)tpos[t*2] * 768, p1 = (long)tpos[t*2+1] * 768;
  for (int d = threadIdx.x; d < 768; d += 256){
    float e0 = ye[p0+d] + ye[espo+p0+d];
    float e1 = ye[p1+d] + ye[espo+p1+d];
    float sv = ys[(long)t*768+d] + ys[sspo+(long)t*768+d];
    out[(long)t*768 + d] = h[(long)t*768 + d] + g2[d] * (w0*e0 + w1*e1 + sv);
  }
}

// =================================================================================
struct Ctx {
  const float *img,*txt,*vec,*imw,*imb,*tmw,*tmb,*iqkvb,*tqkvb,*ipb,*tpb,
              *iqs,*iks,*tqs,*tks,*igw,*tgw;
  const void *iqkvw,*tqkvw,*ipw,*tpw,*ieg,*ieu,*ied,*isg,*isu,*isd,
             *teg,*teu,*ted,*tsg,*tsu,*tsd;
  float *out_img,*out_txt;
  float *mod_i,*mod_t,*h_i,*h_t,*x2f_i,*x2f_t,*tkw_i,*tkw_t;
  bf16  *x2_i,*x2_t;
  int *tki_i,*cnt_i,*ofs_i,*cur_i,*rows_i,*tpos_i;
  int *tki_t,*cnt_t,*ofs_t,*cur_t,*rows_t,*tpos_t;
  bf16 *Qb,*Kb,*Vt,*O,*xm_i,*xm_t,*qr_i,*qr_t,*S,*P;
  float *pj_i,*pj_t;
  bf16 *g_i,*h1_i,*gs_i,*h1s_i,*g_t,*h1_t,*gs_t,*h1s_t;
  float *ye_i,*ys_i,*ye_t,*ys_t;
};

static void seq(const Ctx& c, bool W, hipStream_t s){
  GemmFn Fqkv  = W ? k_qkv_b  : k_qkv_f;
  GemmFn Fproj = W ? k_proj_b : k_proj_f;
  GemmFn Fgate = W ? k_gate_b : k_gate_f;
  GemmFn Fup   = W ? k_up_b   : k_up_f;
  GemmFn Fdown = W ? k_down_b : k_down_f;
  GemmFn Fshg  = W ? k_shg_b  : k_shg_f;
  GemmFn Fshu  = W ? k_shu_b  : k_shu_f;
  GemmFn Fshd  = W ? k_shd_b  : k_shd_f;

  zero_counts_kernel<<<1, 64, 0, s>>>(c.cnt_i, c.cnt_t);
  mod_kernel<<<dim3(576,2), 256, 0, s>>>(c.vec, c.imw, c.imb, c.mod_i);
  mod_kernel<<<dim3(576,2), 256, 0, s>>>(c.vec, c.tmw, c.tmb, c.mod_t);
  ln_mod_kernel<<<2048, 256, 0, s>>>(c.img, c.mod_i, 0, 768, c.xm_i, 1024);
  ln_mod_kernel<<<512,  256, 0, s>>>(c.txt, c.mod_t, 0, 768, c.xm_t, 256);
  Fqkv<<<dim3(18,16,1), 256, 0, s>>>(c.xm_i, nullptr, c.iqkvw, c.iqkvb, c.qr_i,
      2048, 2304, 768, 0, 0, 1, 0, 0, 2304, 1.f, 1, 0, nullptr, nullptr, nullptr);
  Fqkv<<<dim3(18,4,1), 256, 0, s>>>(c.xm_t, nullptr, c.tqkvw, c.tqkvb, c.qr_t,
      512, 2304, 768, 0, 0, 1, 0, 0, 2304, 1.f, 1, 0, nullptr, nullptr, nullptr);
  qkv_scatter_kernel<<<dim3(16,24), 256, 0, s>>>(c.qr_i, c.iqs, c.iks, c.Qb, c.Kb, c.Vt, 1024, 256);
  qkv_scatter_kernel<<<dim3(4,24),  256, 0, s>>>(c.qr_t, c.tqs, c.tks, c.Qb, c.Kb, c.Vt, 256, 0);
  for (int ch = 0; ch < 4; ch++){
    const bf16* Qc = c.Qb + (size_t)ch * 6 * 1280 * 64;
    const bf16* Kc = c.Kb + (size_t)ch * 6 * 1280 * 64;
    const bf16* Vc = c.Vt + (size_t)ch * 6 * 1280 * 64;
    bf16* Oc = c.O + (size_t)(ch >> 1) * 1280 * 768 + (size_t)(ch & 1) * 6 * 64;
    k_qkt<<<dim3(10,10,6), 256, 0, s>>>(Qc, nullptr, (const void*)Kc, nullptr, c.S,
        1280, 1280, 64, (long)1280*64, (long)1280*64, 1, (long)1280*1280, 0, 1280,
        0.125f, 1, 0, nullptr, nullptr, nullptr);
    softmax_kernel<<<6*1280, 256, 0, s>>>(c.S, c.P);
    k_pv<<<dim3(1,10,6), 256, 0, s>>>(c.P, nullptr, (const void*)Vc, nullptr, Oc,
        1280, 64, 1280, (long)1280*1280, (long)64*1280, 6, 0, 64, 768,
        1.f, 1, 0, nullptr, nullptr, nullptr);
  }
  Fproj<<<dim3(6,8,2), 256, 0, s>>>(c.O + (long)256*768, nullptr, c.ipw, c.ipb, c.pj_i,
      1024, 768, 768, (long)1280*768, 0, 1, (long)1024*768, 0, 768, 1.f, 1, 0,
      nullptr, nullptr, nullptr);
  Fproj<<<dim3(6,2,2), 256, 0, s>>>(c.O, nullptr, c.tpw, c.tpb, c.pj_t,
      256, 768, 768, (long)1280*768, 0, 1, (long)256*768, 0, 768, 1.f, 1, 0,
      nullptr, nullptr, nullptr);
  resid_ln_mod_kernel<<<2048, 256, 0, s>>>(c.img, c.pj_i, c.mod_i, c.h_i, c.x2_i, c.x2f_i, 1024);
  resid_ln_mod_kernel<<<512,  256, 0, s>>>(c.txt, c.pj_t, c.mod_t, c.h_t, c.x2_t, c.x2f_t, 256);
  router_kernel<<<512, 256, 0, s>>>(c.x2f_i, c.igw, c.tkw_i, c.tki_i, c.cnt_i, 2048);
  router_kernel<<<128, 256, 0, s>>>(c.x2f_t, c.tgw, c.tkw_t, c.tki_t, c.cnt_t, 512);
  offsets_kernel<<<1, 1, 0, s>>>(c.cnt_i, c.ofs_i, c.cur_i);
  offsets_kernel<<<1, 1, 0, s>>>(c.cnt_t, c.ofs_t, c.cur_t);
  scatter_kernel<<<16, 256, 0, s>>>(c.tki_i, c.ofs_i, c.cur_i, c.rows_i, c.tpos_i, 2048);
  scatter_kernel<<<4,  256, 0, s>>>(c.tki_t, c.ofs_t, c.cur_t, c.rows_t, c.tpos_t, 512);
  // ---- img MoE ----
  Fgate<<<dim3(24,16,8), 256, 0, s>>>(c.x2_i, nullptr, c.ieg, nullptr, c.g_i,
      2048, 3072, 768, 0, (long)3072*768, 1, 0, 0, 3072, 1.f, 1, 0,
      c.rows_i, c.ofs_i, c.cnt_i);
  Fup<<<dim3(24,16,8), 256, 0, s>>>(c.x2_i, c.g_i, c.ieu, nullptr, c.h1_i,
      2048, 3072, 768, 0, (long)3072*768, 1, 0, 0, 3072, 1.f, 1, 0,
      c.rows_i, c.ofs_i, c.cnt_i);
  Fdown<<<dim3(6,16,16), 256, 0, s>>>(c.h1_i, nullptr, c.ied, nullptr, c.ye_i,
      2048, 768, 3072, 0, (long)768*3072, 1, 0, 0, 768, 1.f, 2, (long)4096*768,
      nullptr, c.ofs_i, c.cnt_i);
  Fshg<<<dim3(12,16,1), 256, 0, s>>>(c.x2_i, nullptr, c.isg, nullptr, c.gs_i,
      2048, 1536, 768, 0, 0, 1, 0, 0, 1536, 1.f, 1, 0, nullptr, nullptr, nullptr);
  Fshu<<<dim3(12,16,1), 256, 0, s>>>(c.x2_i, c.gs_i, c.isu, nullptr, c.h1s_i,
      2048, 1536, 768, 0, 0, 1, 0, 0, 1536, 1.f, 1, 0, nullptr, nullptr, nullptr);
  Fshd<<<dim3(6,16,2), 256, 0, s>>>(c.h1s_i, nullptr, c.isd, nullptr, c.ys_i,
      2048, 768, 1536, 0, 0, 1, 0, 0, 768, 1.f, 2, (long)2048*768,
      nullptr, nullptr, nullptr);
  combine_kernel<<<2048, 256, 0, s>>>(c.h_i, c.mod_i, c.tkw_i, c.tpos_i,
      c.ye_i, (long)4096*768, c.ys_i, (long)2048*768, c.out_img, 1024);
  // ---- txt MoE ----
  Fgate<<<dim3(24,4,8), 256, 0, s>>>(c.x2_t, nullptr, c.teg, nullptr, c.g_t,
      512, 3072, 768, 0, (long)3072*768, 1, 0, 0, 3072, 1.f, 1, 0,
      c.rows_t, c.ofs_t, c.cnt_t);
  Fup<<<dim3(24,4,8), 256, 0, s>>>(c.x2_t, c.g_t, c.teu, nullptr, c.h1_t,
      512, 3072, 768, 0, (long)3072*768, 1, 0, 0, 3072, 1.f, 1, 0,
      c.rows_t, c.ofs_t, c.cnt_t);
  Fdown<<<dim3(6,4,16), 256, 0, s>>>(c.h1_t, nullptr, c.ted, nullptr, c.ye_t,
      512, 768, 3072, 0, (long)768*3072, 1, 0, 0, 768, 1.f, 2, (long)1024*768,
      nullptr, c.ofs_t, c.cnt_t);
  Fshg<<<dim3(12,4,1), 256, 0, s>>>(c.x2_t, nullptr, c.tsg, nullptr, c.gs_t,
      512, 1536, 768, 0, 0, 1, 0, 0, 1536, 1.f, 1, 0, nullptr, nullptr, nullptr);
  Fshu<<<dim3(12,4,1), 256, 0, s>>>(c.x2_t, c.gs_t, c.tsu, nullptr, c.h1s_t,
      512, 1536, 768, 0, 0, 1, 0, 0, 1536, 1.f, 1, 0, nullptr, nullptr, nullptr);
  Fshd<<<dim3(6,4,2), 256, 0, s>>>(c.h1s_t, nullptr, c.tsd, nullptr, c.ys_t,
      512, 768, 1536, 0, 0, 1, 0, 0, 768, 1.f, 2, (long)512*768,
      nullptr, nullptr, nullptr);
  combine_kernel<<<512, 256, 0, s>>>(c.h_t, c.mod_t, c.tkw_t, c.tpos_t,
      c.ye_t, (long)1024*768, c.ys_t, (long)512*768, c.out_txt, 256);
}

extern "C" void kernel_launch(void* const* d_in, const int* in_sizes, int n_in,
                              void* d_out, int out_size, void* d_ws, size_t ws_size,
                              hipStream_t stream){
  (void)in_sizes; (void)n_in; (void)out_size;
  const float* fin[33];
  for (int i = 0; i < 33; i++) fin[i] = (const float*)d_in[i];

  char* ws = (char*)d_ws;
  size_t off = 0, peak = 0;
  auto alloc = [&](size_t n)->char*{
    off = (off + 255) & ~(size_t)255;
    char* p = ws + off; off += n;
    if (off > peak) peak = off;
    return p;
  };

  Ctx c{};
  c.img=fin[0]; c.txt=fin[1]; c.vec=fin[2]; c.imw=fin[3]; c.imb=fin[4];
  c.tmw=fin[5]; c.tmb=fin[6]; c.iqkvb=fin[8]; c.ipb=fin[10];
  c.tqkvb=fin[12]; c.tpb=fin[14]; c.iqs=fin[15]; c.iks=fin[16];
  c.tqs=fin[17]; c.tks=fin[18]; c.igw=fin[19]; c.tgw=fin[26];
  c.out_img = (float*)d_out;
  c.out_txt = (float*)d_out + (long)2*1024*768;

  bf16 *wq_i=nullptr,*wq_t=nullptr,*wp_i=nullptr,*wp_t=nullptr;
  bf16 *weg=nullptr,*weu=nullptr,*wed=nullptr,*wtg=nullptr,*wtu=nullptr,*wtd=nullptr;
  bf16 *wsg=nullptr,*wsu=nullptr,*wsd=nullptr,*wtsg=nullptr,*wtsu=nullptr,*wtsd=nullptr;
  auto build = [&](bool W){
    off = 0; peak = 0;
    c.mod_i=(float*)alloc(2*4608*4);  c.mod_t=(float*)alloc(2*4608*4);
    c.h_i  =(float*)alloc((size_t)2048*768*4); c.h_t=(float*)alloc((size_t)512*768*4);
    c.x2_i =(bf16*)alloc((size_t)2048*768*2);  c.x2_t=(bf16*)alloc((size_t)512*768*2);
    c.x2f_i=(float*)alloc((size_t)2048*768*4); c.x2f_t=(float*)alloc((size_t)512*768*4);
    c.tkw_i=(float*)alloc(2048*2*4); c.tki_i=(int*)alloc(2048*2*4);
    c.cnt_i=(int*)alloc(8*4); c.ofs_i=(int*)alloc(8*4); c.cur_i=(int*)alloc(8*4);
    c.rows_i=(int*)alloc(4096*4); c.tpos_i=(int*)alloc(4096*4);
    c.tkw_t=(float*)alloc(512*2*4); c.tki_t=(int*)alloc(512*2*4);
    c.cnt_t=(int*)alloc(8*4); c.ofs_t=(int*)alloc(8*4); c.cur_t=(int*)alloc(8*4);
    c.rows_t=(int*)alloc(1024*4); c.tpos_t=(int*)alloc(1024*4);
    if (W){
      const size_t EB = (size_t)8*3072*768*2;
      weg=(bf16*)alloc(EB); weu=(bf16*)alloc(EB); wed=(bf16*)alloc(EB);
      wtg=(bf16*)alloc(EB); wtu=(bf16*)alloc(EB); wtd=(bf16*)alloc(EB);
      wq_i=(bf16*)alloc((size_t)2304*768*2); wq_t=(bf16*)alloc((size_t)2304*768*2);
      wp_i=(bf16*)alloc((size_t)768*768*2);  wp_t=(bf16*)alloc((size_t)768*768*2);
      wsg=(bf16*)alloc((size_t)1536*768*2);  wsu=(bf16*)alloc((size_t)1536*768*2);
      wsd=(bf16*)alloc((size_t)768*1536*2);
      wtsg=(bf16*)alloc((size_t)1536*768*2); wtsu=(bf16*)alloc((size_t)1536*768*2);
      wtsd=(bf16*)alloc((size_t)768*1536*2);
    }
    size_t arena = (off + 255) & ~(size_t)255;
    // phase A
    off = arena;
    c.Qb=(bf16*)alloc((size_t)24*1280*64*2);
    c.Kb=(bf16*)alloc((size_t)24*1280*64*2);
    c.Vt=(bf16*)alloc((size_t)24*1280*64*2);
    c.O =(bf16*)alloc((size_t)2*1280*768*2);
    c.pj_i=(float*)alloc((size_t)2048*768*4);
    c.pj_t=(float*)alloc((size_t)512*768*4);
    size_t sub = (off + 255) & ~(size_t)255;
    c.xm_i=(bf16*)alloc((size_t)2048*768*2); c.xm_t=(bf16*)alloc((size_t)512*768*2);
    c.qr_i=(bf16*)alloc((size_t)2048*2304*2); c.qr_t=(bf16*)alloc((size_t)512*2304*2);
    off = sub;
    c.S=(bf16*)alloc((size_t)6*1280*1280*2);
    c.P=(bf16*)alloc((size_t)6*1280*1280*2);
    // phase B img (overlays phase A); ye overlays dead g (equal sizes)
    off = arena;
    c.g_i =(bf16*)alloc((size_t)4096*3072*2);
    c.h1_i=(bf16*)alloc((size_t)4096*3072*2);
    c.gs_i=(bf16*)alloc((size_t)2048*1536*2);
    c.h1s_i=(bf16*)alloc((size_t)2048*1536*2);
    c.ys_i=(float*)alloc((size_t)2048*768*4*2);
    c.ye_i=(float*)c.g_i;                       // 4096*768*4*2 == 4096*3072*2
    // phase B txt (overlays img; runs after combine_img)
    off = arena;
    c.g_t =(bf16*)alloc((size_t)1024*3072*2);
    c.h1_t=(bf16*)alloc((size_t)1024*3072*2);
    c.gs_t=(bf16*)alloc((size_t)512*1536*2);
    c.h1s_t=(bf16*)alloc((size_t)512*1536*2);
    c.ys_t=(float*)alloc((size_t)512*768*4*2);
    c.ye_t=(float*)c.g_t;                       // 1024*768*4*2 == 1024*3072*2
  };

  build(true);
  bool W = (peak <= ws_size);
  if (!W) build(false);

  if (W){
    auto cv = [&](const float* src, bf16* dst, long n){
      f2b_kernel<<<(unsigned)((n/8 + 255)/256), 256, 0, stream>>>(src, dst, n);
    };
    const long EN = (long)8*3072*768;
    cv(fin[20], weg, EN); cv(fin[21], weu, EN); cv(fin[22], wed, EN);
    cv(fin[27], wtg, EN); cv(fin[28], wtu, EN); cv(fin[29], wtd, EN);
    cv(fin[7],  wq_i, (long)2304*768); cv(fin[11], wq_t, (long)2304*768);
    cv(fin[9],  wp_i, (long)768*768);  cv(fin[13], wp_t, (long)768*768);
    cv(fin[23], wsg, (long)1536*768);  cv(fin[24], wsu, (long)1536*768);
    cv(fin[25], wsd, (long)768*1536);
    cv(fin[30], wtsg,(long)1536*768);  cv(fin[31], wtsu,(long)1536*768);
    cv(fin[32], wtsd,(long)768*1536);
    c.iqkvw=wq_i; c.tqkvw=wq_t; c.ipw=wp_i; c.tpw=wp_t;
    c.ieg=weg; c.ieu=weu; c.ied=wed; c.teg=wtg; c.teu=wtu; c.ted=wtd;
    c.isg=wsg; c.isu=wsu; c.isd=wsd; c.tsg=wtsg; c.tsu=wtsu; c.tsd=wtsd;
  } else {
    c.iqkvw=fin[7]; c.tqkvw=fin[11]; c.ipw=fin[9]; c.tpw=fin[13];
    c.ieg=fin[20]; c.ieu=fin[21]; c.ied=fin[22];
    c.teg=fin[27]; c.teu=fin[28]; c.ted=fin[29];
    c.isg=fin[23]; c.isu=fin[24]; c.isd=fin[25];
    c.tsg=fin[30]; c.tsu=fin[31]; c.tsd=fin[32];
  }
  seq(c, W, stream);
}

// Round 6
// 1930.857 us; speedup vs baseline: 1.0489x; 1.0489x over previous
//
#include <hip/hip_runtime.h>
#include <hip/hip_bf16.h>

using bf16 = __hip_bfloat16;
typedef __attribute__((ext_vector_type(4))) float f32x4;
typedef __attribute__((ext_vector_type(8))) short s16x8;

#define DEV static __device__ __forceinline__
DEV float bf2f(bf16 x){ return __bfloat162float(x); }
DEV bf16  f2bf(float x){ return __float2bfloat16(x); }
DEV float silu_(float x){ return x / (1.f + expf(-x)); }

// ------------------------------------------------------------------
// Pipelined bf16 MFMA GEMM core:  C = alpha * (A @ B^T) (+ bias)
// A bf16 rows (lda=K). B f32 or bf16 rows (ldb=K).
// EXPERT: Meff=counts[z], rowbase=offsets[z]; GATHER: A row via rowlist.
// OUT: 0 = f32 store, 1 = bf16 store. EPI: v = silu(G[idx]) * v at store.
// ksplit: blockIdx.z = z*ksplit + split; split s writes at +s*c_spo.
// Epilogue: LDS-staged, 16B vector stores (coalesced).
// ------------------------------------------------------------------
template<bool B_F32, bool EXPERT, bool GATHER, int OUT, bool BIAS, bool EPI>
DEV void gemm_core(
    const bf16* __restrict__ A, const bf16* __restrict__ G,
    const void* __restrict__ Bv,
    const float* __restrict__ bias, void* __restrict__ C,
    int M, int N, int K, long a_zoff, long b_zoff,
    int zdiv, long c_so, long c_si, int ldc,
    float alpha, int ksplit, long c_spo,
    const int* __restrict__ rowlist, const int* __restrict__ offsets,
    const int* __restrict__ counts)
{
  __shared__ __align__(16) char smem_[36864];
  bf16 (*As)[72] = (bf16(*)[72])smem_;
  bf16 (*Bs)[72] = (bf16(*)[72])(smem_ + 18432);
  float (*st)[132] = (float(*)[132])smem_;   // 32*132*4 = 16896 B, reused post-loop

  const int zz = blockIdx.z;
  const int z = zz / ksplit, split = zz % ksplit;
  const int m0 = blockIdx.y * 128, n0 = blockIdx.x * 128;
  int Meff = M; long rowbase = 0;
  if (EXPERT){ Meff = counts[z]; rowbase = offsets[z]; }
  if (m0 >= Meff) return;
  const bf16* Ab = A + (EXPERT ? 0 : z * a_zoff);
  long coff;
  if (EXPERT) coff = rowbase * (long)ldc;
  else        coff = (long)(z / zdiv) * c_so + (long)(z % zdiv) * c_si;
  coff += (long)split * c_spo;

  const int klen = K / ksplit;
  const int kbeg = split * klen;
  const int NT = klen >> 6;

  const int tid = threadIdx.x;
  const int lane = tid & 63, wid = tid >> 6;
  const int wm = wid >> 1, wn = wid & 1;

  const int rbase = tid >> 3;
  const int kc = (tid & 7) << 3;
  const bf16* ap[4];
  const bf16* bp[4]; const float* bpf[4];
  bool avalid[4], bvalid[4];
  #pragma unroll
  for (int it = 0; it < 4; it++){
    int row = rbase + 32 * it;
    long ar = 0;
    if (EXPERT){
      int i = m0 + row;
      avalid[it] = i < Meff;
      if (avalid[it]) ar = GATHER ? (long)rowlist[rowbase + i] : (rowbase + i);
    } else {
      avalid[it] = (m0 + row) < Meff;
      ar = m0 + row;
    }
    ap[it] = Ab + ar * (long)K + kbeg + kc;
    bvalid[it] = (n0 + row) < N;
    long br = bvalid[it] ? (long)(n0 + row) : 0;
    if (B_F32) bpf[it] = (const float*)Bv + z * b_zoff + br * K + kbeg + kc;
    else       bp[it]  = (const bf16*) Bv + z * b_zoff + br * K + kbeg + kc;
  }

  uint4 ra[4], rb[4];
  float4 fb0[4], fb1[4];
  const uint4 zero4 = make_uint4(0u,0u,0u,0u);

  auto LOAD = [&](int koff){
    #pragma unroll
    for (int it = 0; it < 4; it++){
      ra[it] = avalid[it] ? *(const uint4*)(ap[it] + koff) : zero4;
      if (B_F32){
        if (bvalid[it]){ fb0[it] = *(const float4*)(bpf[it] + koff);
                         fb1[it] = *(const float4*)(bpf[it] + koff + 4); }
        else { fb0[it] = make_float4(0,0,0,0); fb1[it] = make_float4(0,0,0,0); }
      } else {
        rb[it] = bvalid[it] ? *(const uint4*)(bp[it] + koff) : zero4;
      }
    }
  };
  auto STORE = [&](){
    #pragma unroll
    for (int it = 0; it < 4; it++){
      int row = rbase + 32 * it;
      *(uint4*)(&As[row][kc]) = ra[it];
      if (B_F32){
        union { bf16 h[8]; uint4 v; } u;
        u.h[0]=f2bf(fb0[it].x); u.h[1]=f2bf(fb0[it].y); u.h[2]=f2bf(fb0[it].z); u.h[3]=f2bf(fb0[it].w);
        u.h[4]=f2bf(fb1[it].x); u.h[5]=f2bf(fb1[it].y); u.h[6]=f2bf(fb1[it].z); u.h[7]=f2bf(fb1[it].w);
        *(uint4*)(&Bs[row][kc]) = u.v;
      } else {
        *(uint4*)(&Bs[row][kc]) = rb[it];
      }
    }
  };

  f32x4 acc[4][4] = {};
  LOAD(0);
  for (int t = 0; t < NT; t++){
    STORE();
    __syncthreads();
    if (t + 1 < NT) LOAD((t + 1) << 6);
    #pragma unroll
    for (int ks = 0; ks < 2; ks++){
      const int r16 = lane & 15;
      const int kk = ks * 32 + ((lane >> 4) << 3);
      s16x8 af[4], bfr[4];
      #pragma unroll
      for (int mi = 0; mi < 4; mi++) af[mi]  = *(const s16x8*)(&As[wm*64 + mi*16 + r16][kk]);
      #pragma unroll
      for (int ni = 0; ni < 4; ni++) bfr[ni] = *(const s16x8*)(&Bs[wn*64 + ni*16 + r16][kk]);
      #pragma unroll
      for (int mi = 0; mi < 4; mi++)
        #pragma unroll
        for (int ni = 0; ni < 4; ni++)
          acc[mi][ni] = __builtin_amdgcn_mfma_f32_16x16x32_bf16(af[mi], bfr[ni], acc[mi][ni], 0, 0, 0);
    }
    __syncthreads();
  }

  // ---- LDS-staged coalesced epilogue ----
  const int er = tid >> 3;            // 0..31 staging row
  const int ec = (tid & 7) << 4;      // 0..112 col chunk (16 cols)
  const int erg = m0 + (er & 15) + ((er & 16) ? 64 : 0);   // + mi*16 below
  #pragma unroll
  for (int mi = 0; mi < 4; mi++){
    #pragma unroll
    for (int ni = 0; ni < 4; ni++){
      int lc = wn*64 + ni*16 + (lane & 15);
      float bv = 0.f;
      if (BIAS){
        int colg = n0 + lc;
        if (split == 0 && colg < N) bv = bias[colg];
      }
      #pragma unroll
      for (int i = 0; i < 4; i++){
        int lr = wm*16 + ((lane >> 4) << 2) + i;
        st[lr][lc] = acc[mi][ni][i] * alpha + bv;
      }
    }
    __syncthreads();
    int rg = erg + mi*16;
    int cg = n0 + ec;
    if (rg < Meff && cg < N){
      long base = coff + (long)rg * ldc + cg;
      if (OUT == 0){
        float* dst = (float*)C + base;
        #pragma unroll
        for (int q = 0; q < 4; q++)
          *(float4*)(dst + 4*q) = make_float4(st[er][ec+4*q], st[er][ec+4*q+1],
                                              st[er][ec+4*q+2], st[er][ec+4*q+3]);
      } else {
        float gv[16];
        if (EPI){
          union { bf16 h[8]; uint4 v; } g0, g1;
          g0.v = *(const uint4*)(G + base);
          g1.v = *(const uint4*)(G + base + 8);
          #pragma unroll
          for (int j = 0; j < 8; j++){ gv[j] = silu_(bf2f(g0.h[j])); gv[8+j] = silu_(bf2f(g1.h[j])); }
        }
        union { bf16 h[8]; uint4 v; } o0, o1;
        #pragma unroll
        for (int j = 0; j < 8; j++){
          float v0 = st[er][ec+j];
          float v1 = st[er][ec+8+j];
          if (EPI){ v0 *= gv[j]; v1 *= gv[8+j]; }
          o0.h[j] = f2bf(v0); o1.h[j] = f2bf(v1);
        }
        *(uint4*)((bf16*)C + base)     = o0.v;
        *(uint4*)((bf16*)C + base + 8) = o1.v;
      }
    }
    __syncthreads();
  }
}

#define GEMM_K(NAME, BF32, EXPERT, GATHER, OUT, BIAS, EPI)                         \
__global__ __launch_bounds__(256) void NAME(                                       \
    const bf16* A, const bf16* G, const void* Bv, const float* bias, void* C,      \
    int M, int N, int K, long az, long bz, int zdiv, long cso, long csi, int ldc,  \
    float alpha, int ks, long cspo, const int* rl, const int* ofs, const int* cnt){\
  gemm_core<BF32,EXPERT,GATHER,OUT,BIAS,EPI>(A,G,Bv,bias,C,M,N,K,az,bz,zdiv,cso,   \
      csi,ldc,alpha,ks,cspo,rl,ofs,cnt); }

GEMM_K(k_qkv_b,  false,false,false,1,true ,false)
GEMM_K(k_qkt,    false,false,false,1,false,false)
GEMM_K(k_pv,     false,false,false,1,false,false)
GEMM_K(k_proj_b, false,false,false,0,true ,false)
GEMM_K(k_gate_b, false,true ,true ,1,false,false)
GEMM_K(k_up_b,   false,true ,true ,1,false,true )
GEMM_K(k_down_b, false,true ,false,0,false,false)
GEMM_K(k_shg_b,  false,false,false,1,false,false)
GEMM_K(k_shu_b,  false,false,false,1,false,true )
GEMM_K(k_shd_b,  false,false,false,0,false,false)
GEMM_K(k_qkv_f,  true ,false,false,1,true ,false)
GEMM_K(k_proj_f, true ,false,false,0,true ,false)
GEMM_K(k_gate_f, true ,true ,true ,1,false,false)
GEMM_K(k_up_f,   true ,true ,true ,1,false,true )
GEMM_K(k_down_f, true ,true ,false,0,false,false)
GEMM_K(k_shg_f,  true ,false,false,1,false,false)
GEMM_K(k_shu_f,  true ,false,false,1,false,true )
GEMM_K(k_shd_f,  true ,false,false,0,false,false)

using GemmFn = void(*)(const bf16*, const bf16*, const void*, const float*, void*,
                       int,int,int,long,long,int,long,long,int,float,int,long,
                       const int*, const int*, const int*);

// ---- f32 -> bf16 convert (n % 8 == 0) ------------------------------------------
__global__ __launch_bounds__(256) void f2b_kernel(const float* __restrict__ in,
    bf16* __restrict__ out, long n){
  long i = ((long)blockIdx.x * 256 + threadIdx.x) * 8;
  if (i >= n) return;
  float4 a = *(const float4*)(in + i);
  float4 b = *(const float4*)(in + i + 4);
  union { bf16 h[8]; uint4 v; } u;
  u.h[0]=f2bf(a.x); u.h[1]=f2bf(a.y); u.h[2]=f2bf(a.z); u.h[3]=f2bf(a.w);
  u.h[4]=f2bf(b.x); u.h[5]=f2bf(b.y); u.h[6]=f2bf(b.z); u.h[7]=f2bf(b.w);
  *(uint4*)(out + i) = u.v;
}

// ---- modulation GEMV (wave-per-output, coalesced) ------------------------------
__global__ __launch_bounds__(256) void mod_kernel(const float* __restrict__ vec,
    const float* __restrict__ w, const float* __restrict__ b, float* __restrict__ out){
  int bb = blockIdx.y;
  __shared__ float sv[768];
  int tid = threadIdx.x;
  for (int i = tid; i < 768; i += 256){ float v = vec[bb*768 + i]; sv[i] = v/(1.f+expf(-v)); }
  __syncthreads();
  int w4 = tid >> 6, lane = tid & 63;
  int j0 = blockIdx.x * 8 + w4 * 2;
  for (int jj = 0; jj < 2; jj++){
    int j = j0 + jj;
    const float* wr = w + (long)j * 768;
    float p = 0.f;
    #pragma unroll
    for (int i = 0; i < 12; i++) p += sv[lane + 64*i] * wr[lane + 64*i];
    for (int o = 32; o; o >>= 1) p += __shfl_xor(p, o);
    if (lane == 0) out[bb*4608 + j] = p + b[j];
  }
}

// ---------------- y = (1+c)*LN(x) + s  (bf16 out) --------------------------------
__global__ __launch_bounds__(256) void ln_mod_kernel(const float* __restrict__ x,
    const float* __restrict__ mod, int sOff, int cOff, bf16* __restrict__ y, int L){
  int t = blockIdx.x; int b = t / L;
  const float* xr = x + (long)t * 768;
  __shared__ float red[256];
  int tid = threadIdx.x;
  float v[3]; float s = 0.f;
  #pragma unroll
  for (int i = 0; i < 3; i++){ v[i] = xr[tid + 256*i]; s += v[i]; }
  red[tid] = s; __syncthreads();
  for (int o = 128; o; o >>= 1){ if (tid < o) red[tid] += red[tid+o]; __syncthreads(); }
  float mean = red[0] * (1.f/768.f); __syncthreads();
  float s2 = 0.f;
  #pragma unroll
  for (int i = 0; i < 3; i++){ float d = v[i]-mean; s2 += d*d; }
  red[tid] = s2; __syncthreads();
  for (int o = 128; o; o >>= 1){ if (tid < o) red[tid] += red[tid+o]; __syncthreads(); }
  float rs = rsqrtf(red[0] * (1.f/768.f) + 1e-6f);
  const float* mb = mod + (long)b * 4608;
  #pragma unroll
  for (int i = 0; i < 3; i++){
    int d = tid + 256*i;
    y[(long)t*768 + d] = f2bf((1.f + mb[cOff+d]) * ((v[i]-mean)*rs) + mb[sOff+d]);
  }
}

// ---- h = x + g1*proj ; y = (1+c2)*LN(h) + s2  (bf16 y + f32 yf) -----------------
__global__ __launch_bounds__(256) void resid_ln_mod_kernel(const float* __restrict__ x,
    const float* __restrict__ proj, const float* __restrict__ mod,
    float* __restrict__ h, bf16* __restrict__ y, float* __restrict__ yf, int L){
  int t = blockIdx.x; int b = t / L;
  const float* mb = mod + (long)b * 4608;
  const float* xr = x + (long)t * 768;
  const float* pr = proj + (long)t * 768;
  __shared__ float red[256];
  int tid = threadIdx.x;
  float v[3]; float s = 0.f;
  #pragma unroll
  for (int i = 0; i < 3; i++){
    int d = tid + 256*i;
    float hv = xr[d] + mb[2*768 + d] * pr[d];
    h[(long)t*768 + d] = hv;
    v[i] = hv; s += hv;
  }
  red[tid] = s; __syncthreads();
  for (int o = 128; o; o >>= 1){ if (tid < o) red[tid] += red[tid+o]; __syncthreads(); }
  float mean = red[0] * (1.f/768.f); __syncthreads();
  float s2 = 0.f;
  #pragma unroll
  for (int i = 0; i < 3; i++){ float d = v[i]-mean; s2 += d*d; }
  red[tid] = s2; __syncthreads();
  for (int o = 128; o; o >>= 1){ if (tid < o) red[tid] += red[tid+o]; __syncthreads(); }
  float rs = rsqrtf(red[0] * (1.f/768.f) + 1e-6f);
  #pragma unroll
  for (int i = 0; i < 3; i++){
    int d = tid + 256*i;
    float val = (1.f + mb[4*768+d]) * ((v[i]-mean)*rs) + mb[3*768+d];
    y[(long)t*768 + d] = f2bf(val);
    yf[(long)t*768 + d] = val;
  }
}

// ---- qkv rows -> RMS-normed Q,K + transposed V (coalesced via LDS) --------------
__global__ __launch_bounds__(256) void qkv_scatter_kernel(const bf16* __restrict__ qkv,
    const float* __restrict__ qs, const float* __restrict__ ks,
    bf16* __restrict__ Q, bf16* __restrict__ Kb, bf16* __restrict__ Vt,
    int L, int seqoff){
  __shared__ float vt[64][65];
  int bh = blockIdx.y;
  int b = bh / 12, hh = bh % 12;
  int st = blockIdx.x * 64;
  int w = threadIdx.x >> 6, lane = threadIdx.x & 63;
  float qsc = qs[lane], ksc = ks[lane];
  long qkvbase = (long)b * L * 2304;
  long outbase = (long)bh * 1280 * 64;
  #pragma unroll 4
  for (int i = 0; i < 16; i++){
    int r = w*16 + i;
    int t = st + r;
    const bf16* row = qkv + qkvbase + (long)t * 2304;
    float q = bf2f(row[hh*64 + lane]);
    float k = bf2f(row[768 + hh*64 + lane]);
    float v = bf2f(row[1536 + hh*64 + lane]);
    float q2 = q*q, k2 = k*k;
    for (int o = 32; o; o >>= 1){ q2 += __shfl_xor(q2, o); k2 += __shfl_xor(k2, o); }
    q = q * rsqrtf(q2*(1.f/64.f) + 1e-6f) * qsc;
    k = k * rsqrtf(k2*(1.f/64.f) + 1e-6f) * ksc;
    int seq = seqoff + t;
    Q [outbase + (long)seq*64 + lane] = f2bf(q);
    Kb[outbase + (long)seq*64 + lane] = f2bf(k);
    vt[r][lane] = v;
  }
  __syncthreads();
  #pragma unroll 4
  for (int i = 0; i < 16; i++){
    int d = w*16 + i;
    Vt[outbase + (long)d*1280 + seqoff + st + lane] = f2bf(vt[lane][d]);
  }
}

// ---- row softmax over 1280, bf16 in, bf16 out -----------------------------------
__global__ __launch_bounds__(256) void softmax_kernel(const bf16* __restrict__ S, bf16* __restrict__ P){
  long r = blockIdx.x;
  const bf16* sr = S + r * 1280;
  __shared__ float buf[1280];
  __shared__ float red[256];
  int tid = threadIdx.x;
  float mx = -1e30f;
  for (int i = tid; i < 1280; i += 256){ float v = bf2f(sr[i]); buf[i] = v; mx = fmaxf(mx, v); }
  red[tid] = mx; __syncthreads();
  for (int o = 128; o; o >>= 1){ if (tid < o) red[tid] = fmaxf(red[tid], red[tid+o]); __syncthreads(); }
  float m = red[0]; __syncthreads();
  float s = 0.f;
  for (int i = tid; i < 1280; i += 256){ float e = expf(buf[i] - m); buf[i] = e; s += e; }
  red[tid] = s; __syncthreads();
  for (int o = 128; o; o >>= 1){ if (tid < o) red[tid] += red[tid+o]; __syncthreads(); }
  float inv = 1.f / red[0];
  bf16* pr = P + r * 1280;
  for (int i = tid; i < 1280; i += 256) pr[i] = f2bf(buf[i] * inv);
}

// ---- router ---------------------------------------------------------------------
__global__ __launch_bounds__(256) void router_kernel(const float* __restrict__ x2,
    const float* __restrict__ gw, float* __restrict__ tkw, int* __restrict__ tki,
    int* __restrict__ counts, int T){
  int t = blockIdx.x * 4 + (threadIdx.x >> 6);
  int lane = threadIdx.x & 63;
  if (t >= T) return;
  const float* xr = x2 + (long)t * 768;
  float xs[12];
  #pragma unroll
  for (int i = 0; i < 12; i++) xs[i] = xr[lane + 64*i];
  float sc[8];
  #pragma unroll
  for (int e = 0; e < 8; e++){
    const float* gr = gw + e * 768;
    float p = 0.f;
    #pragma unroll
    for (int i = 0; i < 12; i++) p += xs[i] * gr[lane + 64*i];
    for (int o = 32; o; o >>= 1) p += __shfl_xor(p, o);
    sc[e] = p;
  }
  if (lane == 0){
    float m = sc[0];
    for (int e = 1; e < 8; e++) m = fmaxf(m, sc[e]);
    float s = 0.f;
    for (int e = 0; e < 8; e++){ sc[e] = expf(sc[e] - m); s += sc[e]; }
    float inv = 1.f / s;
    for (int e = 0; e < 8; e++) sc[e] *= inv;
    int i0 = 0;
    for (int e = 1; e < 8; e++) if (sc[e] > sc[i0]) i0 = e;
    int i1 = -1;
    for (int e = 0; e < 8; e++){ if (e == i0) continue; if (i1 < 0 || sc[e] > sc[i1]) i1 = e; }
    tkw[t*2] = sc[i0]; tkw[t*2+1] = sc[i1];
    tki[t*2] = i0;     tki[t*2+1] = i1;
    atomicAdd(&counts[i0], 1); atomicAdd(&counts[i1], 1);
  }
}

__global__ void zero_counts_kernel(int* a, int* b){
  int i = threadIdx.x; if (i < 8){ a[i] = 0; b[i] = 0; }
}

__global__ void offsets_kernel(const int* counts, int* offsets, int* cursor){
  if (threadIdx.x == 0){
    int o = 0;
    for (int e = 0; e < 8; e++){ offsets[e] = o; o += counts[e]; cursor[e] = 0; }
  }
}

__global__ __launch_bounds__(256) void scatter_kernel(const int* __restrict__ tki,
    const int* __restrict__ offsets, int* __restrict__ cursor,
    int* __restrict__ rows, int* __restrict__ tpos, int T){
  int idx = blockIdx.x * 256 + threadIdx.x;
  if (idx >= T * 2) return;
  int t = idx >> 1;
  int e = tki[idx];
  int pos = atomicAdd(&cursor[e], 1);
  int g = offsets[e] + pos;
  rows[g] = t;
  tpos[idx] = g;
}

// ---- out = h + g2 * (w0*(yeA+yeB)[p0] + w1*(yeA+yeB)[p1] + (ysA+ysB)) -----------
__global__ __launch_bounds__(256) void combine_kernel(const float* __restrict__ h,
    const float* __restrict__ mod, const float* __restrict__ tkw, const int* __restrict__ tpos,
    const float* __restrict__ ye, long espo, const float* __restrict__ ys, long sspo,
    float* __restrict__ out, int L){
  int t = blockIdx.x; int b = t / L;
  const float* g2 = mod + (long)b * 4608 + 5*768;
  float w0 = tkw[t*2], w1 = tkw[t*2+1];
  long p0 = (long)tpos[t*2] * 768, p1 = (long)tpos[t*2+1] * 768;
  for (int d = threadIdx.x; d < 768; d += 256){
    float e0 = ye[p0+d] + ye[espo+p0+d];
    float e1 = ye[p1+d] + ye[espo+p1+d];
    float sv = ys[(long)t*768+d] + ys[sspo+(long)t*768+d];
    out[(long)t*768 + d] = h[(long)t*768 + d] + g2[d] * (w0*e0 + w1*e1 + sv);
  }
}

// =================================================================================
struct Ctx {
  const float *img,*txt,*vec,*imw,*imb,*tmw,*tmb,*iqkvb,*tqkvb,*ipb,*tpb,
              *iqs,*iks,*tqs,*tks,*igw,*tgw;
  const void *iqkvw,*tqkvw,*ipw,*tpw,*ieg,*ieu,*ied,*isg,*isu,*isd,
             *teg,*teu,*ted,*tsg,*tsu,*tsd;
  float *out_img,*out_txt;
  float *mod_i,*mod_t,*h_i,*h_t,*x2f_i,*x2f_t,*tkw_i,*tkw_t;
  bf16  *x2_i,*x2_t;
  int *tki_i,*cnt_i,*ofs_i,*cur_i,*rows_i,*tpos_i;
  int *tki_t,*cnt_t,*ofs_t,*cur_t,*rows_t,*tpos_t;
  bf16 *Qb,*Kb,*Vt,*O,*xm_i,*xm_t,*qr_i,*qr_t,*S,*P;
  float *pj_i,*pj_t;
  bf16 *g_i,*h1_i,*gs_i,*h1s_i,*g_t,*h1_t,*gs_t,*h1s_t;
  float *ye_i,*ys_i,*ye_t,*ys_t;
};

static void seq(const Ctx& c, bool W, hipStream_t s){
  GemmFn Fqkv  = W ? k_qkv_b  : k_qkv_f;
  GemmFn Fproj = W ? k_proj_b : k_proj_f;
  GemmFn Fgate = W ? k_gate_b : k_gate_f;
  GemmFn Fup   = W ? k_up_b   : k_up_f;
  GemmFn Fdown = W ? k_down_b : k_down_f;
  GemmFn Fshg  = W ? k_shg_b  : k_shg_f;
  GemmFn Fshu  = W ? k_shu_b  : k_shu_f;
  GemmFn Fshd  = W ? k_shd_b  : k_shd_f;

  zero_counts_kernel<<<1, 64, 0, s>>>(c.cnt_i, c.cnt_t);
  mod_kernel<<<dim3(576,2), 256, 0, s>>>(c.vec, c.imw, c.imb, c.mod_i);
  mod_kernel<<<dim3(576,2), 256, 0, s>>>(c.vec, c.tmw, c.tmb, c.mod_t);
  ln_mod_kernel<<<2048, 256, 0, s>>>(c.img, c.mod_i, 0, 768, c.xm_i, 1024);
  ln_mod_kernel<<<512,  256, 0, s>>>(c.txt, c.mod_t, 0, 768, c.xm_t, 256);
  Fqkv<<<dim3(18,16,1), 256, 0, s>>>(c.xm_i, nullptr, c.iqkvw, c.iqkvb, c.qr_i,
      2048, 2304, 768, 0, 0, 1, 0, 0, 2304, 1.f, 1, 0, nullptr, nullptr, nullptr);
  Fqkv<<<dim3(18,4,1), 256, 0, s>>>(c.xm_t, nullptr, c.tqkvw, c.tqkvb, c.qr_t,
      512, 2304, 768, 0, 0, 1, 0, 0, 2304, 1.f, 1, 0, nullptr, nullptr, nullptr);
  qkv_scatter_kernel<<<dim3(16,24), 256, 0, s>>>(c.qr_i, c.iqs, c.iks, c.Qb, c.Kb, c.Vt, 1024, 256);
  qkv_scatter_kernel<<<dim3(4,24),  256, 0, s>>>(c.qr_t, c.tqs, c.tks, c.Qb, c.Kb, c.Vt, 256, 0);
  for (int ch = 0; ch < 4; ch++){
    const bf16* Qc = c.Qb + (size_t)ch * 6 * 1280 * 64;
    const bf16* Kc = c.Kb + (size_t)ch * 6 * 1280 * 64;
    const bf16* Vc = c.Vt + (size_t)ch * 6 * 1280 * 64;
    bf16* Oc = c.O + (size_t)(ch >> 1) * 1280 * 768 + (size_t)(ch & 1) * 6 * 64;
    k_qkt<<<dim3(10,10,6), 256, 0, s>>>(Qc, nullptr, (const void*)Kc, nullptr, c.S,
        1280, 1280, 64, (long)1280*64, (long)1280*64, 1, (long)1280*1280, 0, 1280,
        0.125f, 1, 0, nullptr, nullptr, nullptr);
    softmax_kernel<<<6*1280, 256, 0, s>>>(c.S, c.P);
    k_pv<<<dim3(1,10,6), 256, 0, s>>>(c.P, nullptr, (const void*)Vc, nullptr, Oc,
        1280, 64, 1280, (long)1280*1280, (long)64*1280, 6, 0, 64, 768,
        1.f, 1, 0, nullptr, nullptr, nullptr);
  }
  Fproj<<<dim3(6,8,2), 256, 0, s>>>(c.O + (long)256*768, nullptr, c.ipw, c.ipb, c.pj_i,
      1024, 768, 768, (long)1280*768, 0, 1, (long)1024*768, 0, 768, 1.f, 1, 0,
      nullptr, nullptr, nullptr);
  Fproj<<<dim3(6,2,2), 256, 0, s>>>(c.O, nullptr, c.tpw, c.tpb, c.pj_t,
      256, 768, 768, (long)1280*768, 0, 1, (long)256*768, 0, 768, 1.f, 1, 0,
      nullptr, nullptr, nullptr);
  resid_ln_mod_kernel<<<2048, 256, 0, s>>>(c.img, c.pj_i, c.mod_i, c.h_i, c.x2_i, c.x2f_i, 1024);
  resid_ln_mod_kernel<<<512,  256, 0, s>>>(c.txt, c.pj_t, c.mod_t, c.h_t, c.x2_t, c.x2f_t, 256);
  router_kernel<<<512, 256, 0, s>>>(c.x2f_i, c.igw, c.tkw_i, c.tki_i, c.cnt_i, 2048);
  router_kernel<<<128, 256, 0, s>>>(c.x2f_t, c.tgw, c.tkw_t, c.tki_t, c.cnt_t, 512);
  offsets_kernel<<<1, 1, 0, s>>>(c.cnt_i, c.ofs_i, c.cur_i);
  offsets_kernel<<<1, 1, 0, s>>>(c.cnt_t, c.ofs_t, c.cur_t);
  scatter_kernel<<<16, 256, 0, s>>>(c.tki_i, c.ofs_i, c.cur_i, c.rows_i, c.tpos_i, 2048);
  scatter_kernel<<<4,  256, 0, s>>>(c.tki_t, c.ofs_t, c.cur_t, c.rows_t, c.tpos_t, 512);
  // ---- img MoE ----
  Fgate<<<dim3(24,16,8), 256, 0, s>>>(c.x2_i, nullptr, c.ieg, nullptr, c.g_i,
      2048, 3072, 768, 0, (long)3072*768, 1, 0, 0, 3072, 1.f, 1, 0,
      c.rows_i, c.ofs_i, c.cnt_i);
  Fup<<<dim3(24,16,8), 256, 0, s>>>(c.x2_i, c.g_i, c.ieu, nullptr, c.h1_i,
      2048, 3072, 768, 0, (long)3072*768, 1, 0, 0, 3072, 1.f, 1, 0,
      c.rows_i, c.ofs_i, c.cnt_i);
  Fdown<<<dim3(6,16,16), 256, 0, s>>>(c.h1_i, nullptr, c.ied, nullptr, c.ye_i,
      2048, 768, 3072, 0, (long)768*3072, 1, 0, 0, 768, 1.f, 2, (long)4096*768,
      nullptr, c.ofs_i, c.cnt_i);
  Fshg<<<dim3(12,16,1), 256, 0, s>>>(c.x2_i, nullptr, c.isg, nullptr, c.gs_i,
      2048, 1536, 768, 0, 0, 1, 0, 0, 1536, 1.f, 1, 0, nullptr, nullptr, nullptr);
  Fshu<<<dim3(12,16,1), 256, 0, s>>>(c.x2_i, c.gs_i, c.isu, nullptr, c.h1s_i,
      2048, 1536, 768, 0, 0, 1, 0, 0, 1536, 1.f, 1, 0, nullptr, nullptr, nullptr);
  Fshd<<<dim3(6,16,2), 256, 0, s>>>(c.h1s_i, nullptr, c.isd, nullptr, c.ys_i,
      2048, 768, 1536, 0, 0, 1, 0, 0, 768, 1.f, 2, (long)2048*768,
      nullptr, nullptr, nullptr);
  combine_kernel<<<2048, 256, 0, s>>>(c.h_i, c.mod_i, c.tkw_i, c.tpos_i,
      c.ye_i, (long)4096*768, c.ys_i, (long)2048*768, c.out_img, 1024);
  // ---- txt MoE ----
  Fgate<<<dim3(24,4,8), 256, 0, s>>>(c.x2_t, nullptr, c.teg, nullptr, c.g_t,
      512, 3072, 768, 0, (long)3072*768, 1, 0, 0, 3072, 1.f, 1, 0,
      c.rows_t, c.ofs_t, c.cnt_t);
  Fup<<<dim3(24,4,8), 256, 0, s>>>(c.x2_t, c.g_t, c.teu, nullptr, c.h1_t,
      512, 3072, 768, 0, (long)3072*768, 1, 0, 0, 3072, 1.f, 1, 0,
      c.rows_t, c.ofs_t, c.cnt_t);
  Fdown<<<dim3(6,4,16), 256, 0, s>>>(c.h1_t, nullptr, c.ted, nullptr, c.ye_t,
      512, 768, 3072, 0, (long)768*3072, 1, 0, 0, 768, 1.f, 2, (long)1024*768,
      nullptr, c.ofs_t, c.cnt_t);
  Fshg<<<dim3(12,4,1), 256, 0, s>>>(c.x2_t, nullptr, c.tsg, nullptr, c.gs_t,
      512, 1536, 768, 0, 0, 1, 0, 0, 1536, 1.f, 1, 0, nullptr, nullptr, nullptr);
  Fshu<<<dim3(12,4,1), 256, 0, s>>>(c.x2_t, c.gs_t, c.tsu, nullptr, c.h1s_t,
      512, 1536, 768, 0, 0, 1, 0, 0, 1536, 1.f, 1, 0, nullptr, nullptr, nullptr);
  Fshd<<<dim3(6,4,2), 256, 0, s>>>(c.h1s_t, nullptr, c.tsd, nullptr, c.ys_t,
      512, 768, 1536, 0, 0, 1, 0, 0, 768, 1.f, 2, (long)512*768,
      nullptr, nullptr, nullptr);
  combine_kernel<<<512, 256, 0, s>>>(c.h_t, c.mod_t, c.tkw_t, c.tpos_t,
      c.ye_t, (long)1024*768, c.ys_t, (long)512*768, c.out_txt, 256);
}

extern "C" void kernel_launch(void* const* d_in, const int* in_sizes, int n_in,
                              void* d_out, int out_size, void* d_ws, size_t ws_size,
                              hipStream_t stream){
  (void)in_sizes; (void)n_in; (void)out_size;
  const float* fin[33];
  for (int i = 0; i < 33; i++) fin[i] = (const float*)d_in[i];

  char* ws = (char*)d_ws;
  size_t off = 0, peak = 0;
  auto alloc = [&](size_t n)->char*{
    off = (off + 255) & ~(size_t)255;
    char* p = ws + off; off += n;
    if (off > peak) peak = off;
    return p;
  };

  Ctx c{};
  c.img=fin[0]; c.txt=fin[1]; c.vec=fin[2]; c.imw=fin[3]; c.imb=fin[4];
  c.tmw=fin[5]; c.tmb=fin[6]; c.iqkvb=fin[8]; c.ipb=fin[10];
  c.tqkvb=fin[12]; c.tpb=fin[14]; c.iqs=fin[15]; c.iks=fin[16];
  c.tqs=fin[17]; c.tks=fin[18]; c.igw=fin[19]; c.tgw=fin[26];
  c.out_img = (float*)d_out;
  c.out_txt = (float*)d_out + (long)2*1024*768;

  bf16 *wq_i=nullptr,*wq_t=nullptr,*wp_i=nullptr,*wp_t=nullptr;
  bf16 *weg=nullptr,*weu=nullptr,*wed=nullptr,*wtg=nullptr,*wtu=nullptr,*wtd=nullptr;
  bf16 *wsg=nullptr,*wsu=nullptr,*wsd=nullptr,*wtsg=nullptr,*wtsu=nullptr,*wtsd=nullptr;
  auto build = [&](bool W){
    off = 0; peak = 0;
    c.mod_i=(float*)alloc(2*4608*4);  c.mod_t=(float*)alloc(2*4608*4);
    c.h_i  =(float*)alloc((size_t)2048*768*4); c.h_t=(float*)alloc((size_t)512*768*4);
    c.x2_i =(bf16*)alloc((size_t)2048*768*2);  c.x2_t=(bf16*)alloc((size_t)512*768*2);
    c.x2f_i=(float*)alloc((size_t)2048*768*4); c.x2f_t=(float*)alloc((size_t)512*768*4);
    c.tkw_i=(float*)alloc(2048*2*4); c.tki_i=(int*)alloc(2048*2*4);
    c.cnt_i=(int*)alloc(8*4); c.ofs_i=(int*)alloc(8*4); c.cur_i=(int*)alloc(8*4);
    c.rows_i=(int*)alloc(4096*4); c.tpos_i=(int*)alloc(4096*4);
    c.tkw_t=(float*)alloc(512*2*4); c.tki_t=(int*)alloc(512*2*4);
    c.cnt_t=(int*)alloc(8*4); c.ofs_t=(int*)alloc(8*4); c.cur_t=(int*)alloc(8*4);
    c.rows_t=(int*)alloc(1024*4); c.tpos_t=(int*)alloc(1024*4);
    if (W){
      const size_t EB = (size_t)8*3072*768*2;
      weg=(bf16*)alloc(EB); weu=(bf16*)alloc(EB); wed=(bf16*)alloc(EB);
      wtg=(bf16*)alloc(EB); wtu=(bf16*)alloc(EB); wtd=(bf16*)alloc(EB);
      wq_i=(bf16*)alloc((size_t)2304*768*2); wq_t=(bf16*)alloc((size_t)2304*768*2);
      wp_i=(bf16*)alloc((size_t)768*768*2);  wp_t=(bf16*)alloc((size_t)768*768*2);
      wsg=(bf16*)alloc((size_t)1536*768*2);  wsu=(bf16*)alloc((size_t)1536*768*2);
      wsd=(bf16*)alloc((size_t)768*1536*2);
      wtsg=(bf16*)alloc((size_t)1536*768*2); wtsu=(bf16*)alloc((size_t)1536*768*2);
      wtsd=(bf16*)alloc((size_t)768*1536*2);
    }
    size_t arena = (off + 255) & ~(size_t)255;
    // phase A
    off = arena;
    c.Qb=(bf16*)alloc((size_t)24*1280*64*2);
    c.Kb=(bf16*)alloc((size_t)24*1280*64*2);
    c.Vt=(bf16*)alloc((size_t)24*1280*64*2);
    c.O =(bf16*)alloc((size_t)2*1280*768*2);
    c.pj_i=(float*)alloc((size_t)2048*768*4);
    c.pj_t=(float*)alloc((size_t)512*768*4);
    size_t sub = (off + 255) & ~(size_t)255;
    c.xm_i=(bf16*)alloc((size_t)2048*768*2); c.xm_t=(bf16*)alloc((size_t)512*768*2);
    c.qr_i=(bf16*)alloc((size_t)2048*2304*2); c.qr_t=(bf16*)alloc((size_t)512*2304*2);
    off = sub;
    c.S=(bf16*)alloc((size_t)6*1280*1280*2);
    c.P=(bf16*)alloc((size_t)6*1280*1280*2);
    // phase B img (overlays phase A); ye overlays dead g (equal sizes)
    off = arena;
    c.g_i =(bf16*)alloc((size_t)4096*3072*2);
    c.h1_i=(bf16*)alloc((size_t)4096*3072*2);
    c.gs_i=(bf16*)alloc((size_t)2048*1536*2);
    c.h1s_i=(bf16*)alloc((size_t)2048*1536*2);
    c.ys_i=(float*)alloc((size_t)2048*768*4*2);
    c.ye_i=(float*)c.g_i;                       // 4096*768*4*2 == 4096*3072*2
    // phase B txt (overlays img; runs after combine_img)
    off = arena;
    c.g_t =(bf16*)alloc((size_t)1024*3072*2);
    c.h1_t=(bf16*)alloc((size_t)1024*3072*2);
    c.gs_t=(bf16*)alloc((size_t)512*1536*2);
    c.h1s_t=(bf16*)alloc((size_t)512*1536*2);
    c.ys_t=(float*)alloc((size_t)512*768*4*2);
    c.ye_t=(float*)c.g_t;                       // 1024*768*4*2 == 1024*3072*2
  };

  build(true);
  bool W = (peak <= ws_size);
  if (!W) build(false);

  if (W){
    auto cv = [&](const float* src, bf16* dst, long n){
      f2b_kernel<<<(unsigned)((n/8 + 255)/256), 256, 0, stream>>>(src, dst, n);
    };
    const long EN = (long)8*3072*768;
    cv(fin[20], weg, EN); cv(fin[21], weu, EN); cv(fin[22], wed, EN);
    cv(fin[27], wtg, EN); cv(fin[28], wtu, EN); cv(fin[29], wtd, EN);
    cv(fin[7],  wq_i, (long)2304*768); cv(fin[11], wq_t, (long)2304*768);
    cv(fin[9],  wp_i, (long)768*768);  cv(fin[13], wp_t, (long)768*768);
    cv(fin[23], wsg, (long)1536*768);  cv(fin[24], wsu, (long)1536*768);
    cv(fin[25], wsd, (long)768*1536);
    cv(fin[30], wtsg,(long)1536*768);  cv(fin[31], wtsu,(long)1536*768);
    cv(fin[32], wtsd,(long)768*1536);
    c.iqkvw=wq_i; c.tqkvw=wq_t; c.ipw=wp_i; c.tpw=wp_t;
    c.ieg=weg; c.ieu=weu; c.ied=wed; c.teg=wtg; c.teu=wtu; c.ted=wtd;
    c.isg=wsg; c.isu=wsu; c.isd=wsd; c.tsg=wtsg; c.tsu=wtsu; c.tsd=wtsd;
  } else {
    c.iqkvw=fin[7]; c.tqkvw=fin[11]; c.ipw=fin[9]; c.tpw=fin[13];
    c.ieg=fin[20]; c.ieu=fin[21]; c.ied=fin[22];
    c.teg=fin[27]; c.teu=fin[28]; c.ted=fin[29];
    c.isg=fin[23]; c.isu=fin[24]; c.isd=fin[25];
    c.tsg=fin[30]; c.tsu=fin[31]; c.tsd=fin[32];
  }
  seq(c, W, stream);
}

// Round 7
// 1160.748 us; speedup vs baseline: 1.7447x; 1.6635x over previous
//
#include <hip/hip_runtime.h>
#include <hip/hip_bf16.h>

using bf16 = __hip_bfloat16;
typedef __attribute__((ext_vector_type(4))) float f32x4;
typedef __attribute__((ext_vector_type(8))) short s16x8;

#define DEV static __device__ __forceinline__
DEV float bf2f(bf16 x){ return __bfloat162float(x); }
DEV bf16  f2bf(float x){ return __float2bfloat16(x); }
DEV float silu_(float x){ return x / (1.f + expf(-x)); }

// ------------------------------------------------------------------
// Pipelined bf16 MFMA GEMM core:  C = alpha * (A @ B^T) (+ bias)
// A bf16 rows (lda=K). B (and B2 when GU) f32 or bf16 rows (ldb=K).
// EXPERT: Meff=counts[z], rowbase=offsets[z]; GATHER: A row via rowlist.
// GU: two B panels time-sharing LDS; writes silu(accB)*accB2.
// OUT: 0 = f32 store, 1 = bf16 store.  bidx = z >> bshift selects B panel
// group and bias slice (bias + bidx*biasz).
// ksplit: blockIdx.z = z*ksplit + split; split writes at +split*c_spo.
// ------------------------------------------------------------------
template<bool B_F32, bool EXPERT, bool GATHER, int OUT, bool BIAS, bool GU>
DEV void gemm_core(
    const bf16* __restrict__ A, const void* __restrict__ Bv,
    const void* __restrict__ B2v,
    const float* __restrict__ bias, void* __restrict__ C,
    int M, int N, int K, long a_zoff, long b_zoff, int bshift, int biasz,
    int zdiv, long c_so, long c_si, int ldc,
    float alpha, int ksplit, long c_spo,
    const int* __restrict__ rowlist, const int* __restrict__ offsets,
    const int* __restrict__ counts)
{
  __shared__ __align__(16) char smem_[36864];
  bf16 (*As)[72] = (bf16(*)[72])smem_;
  bf16 (*Bs)[72] = (bf16(*)[72])(smem_ + 18432);
  float (*st)[132] = (float(*)[132])smem_;

  const int zz = blockIdx.z;
  const int z = zz / ksplit, split = zz % ksplit;
  const int m0 = blockIdx.y * 128, n0 = blockIdx.x * 128;
  int Meff = M; long rowbase = 0;
  if (EXPERT){ Meff = counts[z]; rowbase = offsets[z]; }
  if (m0 >= Meff) return;
  const bf16* Ab = A + (EXPERT ? 0 : z * a_zoff);
  const int bidx = z >> bshift;
  long coff;
  if (EXPERT) coff = rowbase * (long)ldc;
  else        coff = (long)(z / zdiv) * c_so + (long)(z % zdiv) * c_si;
  coff += (long)split * c_spo;
  const float* bias_eff = BIAS ? bias + (long)bidx * biasz : nullptr;

  const int klen = K / ksplit;
  const int kbeg = split * klen;
  const int NT = klen >> 6;

  const int tid = threadIdx.x;
  const int lane = tid & 63, wid = tid >> 6;
  const int wm = wid >> 1, wn = wid & 1;

  const int rbase = tid >> 3;
  const int kc = (tid & 7) << 3;
  const bf16* ap[4];
  const bf16* bp[4];  const float* bpf[4];
  const bf16* bp2[4]; const float* bpf2[4];
  bool avalid[4], bvalid[4];
  #pragma unroll
  for (int it = 0; it < 4; it++){
    int row = rbase + 32 * it;
    long ar = 0;
    if (EXPERT){
      int i = m0 + row;
      avalid[it] = i < Meff;
      if (avalid[it]) ar = GATHER ? (long)rowlist[rowbase + i] : (rowbase + i);
    } else {
      avalid[it] = (m0 + row) < Meff;
      ar = m0 + row;
    }
    ap[it] = Ab + ar * (long)K + kbeg + kc;
    bvalid[it] = (n0 + row) < N;
    long br = bvalid[it] ? (long)(n0 + row) : 0;
    if (B_F32){
      bpf[it] = (const float*)Bv + bidx * b_zoff + br * K + kbeg + kc;
      if (GU) bpf2[it] = (const float*)B2v + bidx * b_zoff + br * K + kbeg + kc;
    } else {
      bp[it]  = (const bf16*)Bv + bidx * b_zoff + br * K + kbeg + kc;
      if (GU) bp2[it] = (const bf16*)B2v + bidx * b_zoff + br * K + kbeg + kc;
    }
  }

  uint4 ra[4], rb[4], rb2[4];
  float4 fb0[4], fb1[4], f20[4], f21[4];
  const uint4 zero4 = make_uint4(0u,0u,0u,0u);

  auto LOADA = [&](int koff){
    #pragma unroll
    for (int it = 0; it < 4; it++)
      ra[it] = avalid[it] ? *(const uint4*)(ap[it] + koff) : zero4;
  };
  auto LOADB = [&](int koff){
    #pragma unroll
    for (int it = 0; it < 4; it++){
      if (B_F32){
        if (bvalid[it]){ fb0[it] = *(const float4*)(bpf[it] + koff);
                         fb1[it] = *(const float4*)(bpf[it] + koff + 4); }
        else { fb0[it] = make_float4(0,0,0,0); fb1[it] = make_float4(0,0,0,0); }
      } else rb[it] = bvalid[it] ? *(const uint4*)(bp[it] + koff) : zero4;
    }
  };
  auto LOADB2 = [&](int koff){
    #pragma unroll
    for (int it = 0; it < 4; it++){
      if (B_F32){
        if (bvalid[it]){ f20[it] = *(const float4*)(bpf2[it] + koff);
                         f21[it] = *(const float4*)(bpf2[it] + koff + 4); }
        else { f20[it] = make_float4(0,0,0,0); f21[it] = make_float4(0,0,0,0); }
      } else rb2[it] = bvalid[it] ? *(const uint4*)(bp2[it] + koff) : zero4;
    }
  };
  auto cvt = [&](float4 a, float4 b)->uint4{
    union { bf16 h[8]; uint4 v; } u;
    u.h[0]=f2bf(a.x); u.h[1]=f2bf(a.y); u.h[2]=f2bf(a.z); u.h[3]=f2bf(a.w);
    u.h[4]=f2bf(b.x); u.h[5]=f2bf(b.y); u.h[6]=f2bf(b.z); u.h[7]=f2bf(b.w);
    return u.v;
  };
  auto STOREA = [&](){
    #pragma unroll
    for (int it = 0; it < 4; it++) *(uint4*)(&As[rbase + 32*it][kc]) = ra[it];
  };
  auto STOREB = [&](){
    #pragma unroll
    for (int it = 0; it < 4; it++)
      *(uint4*)(&Bs[rbase + 32*it][kc]) = B_F32 ? cvt(fb0[it], fb1[it]) : rb[it];
  };
  auto STOREB2 = [&](){
    #pragma unroll
    for (int it = 0; it < 4; it++)
      *(uint4*)(&Bs[rbase + 32*it][kc]) = B_F32 ? cvt(f20[it], f21[it]) : rb2[it];
  };

  f32x4 acc[4][4] = {};
  f32x4 acc2[4][4] = {};
  auto MFMA = [&](f32x4 (&ac)[4][4]){
    #pragma unroll
    for (int ks2 = 0; ks2 < 2; ks2++){
      const int r16 = lane & 15;
      const int kk = ks2 * 32 + ((lane >> 4) << 3);
      s16x8 af[4], bfr[4];
      #pragma unroll
      for (int mi = 0; mi < 4; mi++) af[mi]  = *(const s16x8*)(&As[wm*64 + mi*16 + r16][kk]);
      #pragma unroll
      for (int ni = 0; ni < 4; ni++) bfr[ni] = *(const s16x8*)(&Bs[wn*64 + ni*16 + r16][kk]);
      #pragma unroll
      for (int mi = 0; mi < 4; mi++)
        #pragma unroll
        for (int ni = 0; ni < 4; ni++)
          ac[mi][ni] = __builtin_amdgcn_mfma_f32_16x16x32_bf16(af[mi], bfr[ni], ac[mi][ni], 0, 0, 0);
    }
  };

  LOADA(0); LOADB(0);
  for (int t = 0; t < NT; t++){
    STOREA(); STOREB();
    __syncthreads();
    if (GU){
      LOADB2(t << 6);
      MFMA(acc);
      __syncthreads();
      STOREB2();
      __syncthreads();
      if (t + 1 < NT){ LOADA((t+1) << 6); LOADB((t+1) << 6); }
      MFMA(acc2);
      __syncthreads();
    } else {
      if (t + 1 < NT){ LOADA((t+1) << 6); LOADB((t+1) << 6); }
      MFMA(acc);
      __syncthreads();
    }
  }

  // ---- LDS-staged coalesced epilogue ----
  const int er = tid >> 3;
  const int ec = (tid & 7) << 4;
  const int erg = m0 + (er & 15) + ((er & 16) ? 64 : 0);
  #pragma unroll
  for (int mi = 0; mi < 4; mi++){
    #pragma unroll
    for (int ni = 0; ni < 4; ni++){
      int lc = wn*64 + ni*16 + (lane & 15);
      float bv = 0.f;
      if (BIAS){ if (split == 0) bv = bias_eff[n0 + lc]; }
      #pragma unroll
      for (int i = 0; i < 4; i++){
        int lr = wm*16 + ((lane >> 4) << 2) + i;
        float v;
        if (GU) v = silu_(acc[mi][ni][i]) * acc2[mi][ni][i];
        else    v = acc[mi][ni][i] * alpha + bv;
        st[lr][lc] = v;
      }
    }
    __syncthreads();
    int rg = erg + mi*16;
    int cg = n0 + ec;
    if (rg < Meff && cg < N){
      long base = coff + (long)rg * ldc + cg;
      if (OUT == 0){
        float* dst = (float*)C + base;
        #pragma unroll
        for (int q = 0; q < 4; q++)
          *(float4*)(dst + 4*q) = make_float4(st[er][ec+4*q], st[er][ec+4*q+1],
                                              st[er][ec+4*q+2], st[er][ec+4*q+3]);
      } else {
        union { bf16 h[8]; uint4 v; } o0, o1;
        #pragma unroll
        for (int j = 0; j < 8; j++){
          o0.h[j] = f2bf(st[er][ec+j]);
          o1.h[j] = f2bf(st[er][ec+8+j]);
        }
        *(uint4*)((bf16*)C + base)     = o0.v;
        *(uint4*)((bf16*)C + base + 8) = o1.v;
      }
    }
    __syncthreads();
  }
}

#define GEMM_K(NAME, BF32, EXPERT, GATHER, OUT, BIAS, GU)                          \
__global__ __launch_bounds__(256) void NAME(                                       \
    const bf16* A, const void* Bv, const void* B2v, const float* bias, void* C,    \
    int M, int N, int K, long az, long bz, int bshift, int biasz,                  \
    int zdiv, long cso, long csi, int ldc, float alpha, int ks, long cspo,         \
    const int* rl, const int* ofs, const int* cnt){                                \
  gemm_core<BF32,EXPERT,GATHER,OUT,BIAS,GU>(A,Bv,B2v,bias,C,M,N,K,az,bz,bshift,    \
      biasz,zdiv,cso,csi,ldc,alpha,ks,cspo,rl,ofs,cnt); }

// tier A (bf16 weights)
GEMM_K(k_qkv_b,  false,true ,false,1,true ,false)
GEMM_K(k_qkt,    false,false,false,1,false,false)
GEMM_K(k_pv,     false,false,false,0,false,false)
GEMM_K(k_proj_b, false,true ,false,0,true ,false)
GEMM_K(k_gu_b,   false,true ,true ,1,false,true )
GEMM_K(k_down_b, false,true ,false,0,false,false)
GEMM_K(k_sgu_b,  false,true ,false,1,false,true )
GEMM_K(k_sdown_b,false,true ,false,0,false,false)
// tier B (f32 weights)
GEMM_K(k_qkv_f,  true ,true ,false,1,true ,false)
GEMM_K(k_proj_f, true ,true ,false,0,true ,false)
GEMM_K(k_gu_f,   true ,true ,true ,1,false,true )
GEMM_K(k_down_f, true ,true ,false,0,false,false)
GEMM_K(k_sgu_f,  true ,true ,false,1,false,true )
GEMM_K(k_sdown_f,true ,true ,false,0,false,false)

// ---- init / tables ----
__global__ void init_kernel(int* cnt16, int* tabs){
  int i = threadIdx.x;
  if (i < 16) cnt16[i] = 0;
  if (i == 0){
    tabs[0]=2048; tabs[1]=512; tabs[2]=0; tabs[3]=2048;          // qkv cnt/ofs
    tabs[4]=256; tabs[5]=256; tabs[6]=1024; tabs[7]=1024;        // proj cnt
    tabs[8]=0; tabs[9]=1280; tabs[10]=256; tabs[11]=1536;        // proj ofs
    tabs[12]=2048; tabs[13]=512; tabs[14]=0; tabs[15]=2048;      // shared cnt/ofs
  }
}
__global__ void tables_kernel(const int* cnt16, int* ofs16, int* cur16){
  if (threadIdx.x == 0){
    int o = 0;
    for (int e = 0; e < 8; e++){ ofs16[e] = o; o += cnt16[e]; cur16[e] = 0; }
    o = 4096;
    for (int e = 8; e < 16; e++){ ofs16[e] = o; o += cnt16[e]; cur16[e] = 0; }
  }
}

// ---- f32 -> bf16 convert ----
__global__ __launch_bounds__(256) void f2b_kernel(const float* __restrict__ in,
    bf16* __restrict__ out, long n){
  long i = ((long)blockIdx.x * 256 + threadIdx.x) * 8;
  if (i >= n) return;
  float4 a = *(const float4*)(in + i);
  float4 b = *(const float4*)(in + i + 4);
  union { bf16 h[8]; uint4 v; } u;
  u.h[0]=f2bf(a.x); u.h[1]=f2bf(a.y); u.h[2]=f2bf(a.z); u.h[3]=f2bf(a.w);
  u.h[4]=f2bf(b.x); u.h[5]=f2bf(b.y); u.h[6]=f2bf(b.z); u.h[7]=f2bf(b.w);
  *(uint4*)(out + i) = u.v;
}

// ---- O partial reduce: Opart[10][6][1280][64] f32 -> O bf16 --------------------
__global__ __launch_bounds__(256) void reduce_o_kernel(const float* __restrict__ Op,
    bf16* __restrict__ O, int chunk){
  int z = blockIdx.y;
  int bh = chunk*6 + z;
  int b = bh / 12, hh = bh % 12;
  int d = threadIdx.x & 63, rr = threadIdx.x >> 6;
  const float* base = Op + (long)z * 1280 * 64;
  #pragma unroll
  for (int j = 0; j < 4; j++){
    int row = blockIdx.x * 16 + rr * 4 + j;
    float s = 0.f;
    #pragma unroll
    for (int sp = 0; sp < 10; sp++) s += base[(long)sp*6*1280*64 + (long)row*64 + d];
    O[((long)b*1280 + row)*768 + hh*64 + d] = f2bf(s);
  }
}

// ---- modulation GEMV ----
__global__ __launch_bounds__(256) void mod_kernel(const float* __restrict__ vec,
    const float* __restrict__ w, const float* __restrict__ b, float* __restrict__ out){
  int bb = blockIdx.y;
  __shared__ float sv[768];
  int tid = threadIdx.x;
  for (int i = tid; i < 768; i += 256){ float v = vec[bb*768 + i]; sv[i] = v/(1.f+expf(-v)); }
  __syncthreads();
  int w4 = tid >> 6, lane = tid & 63;
  int j0 = blockIdx.x * 8 + w4 * 2;
  for (int jj = 0; jj < 2; jj++){
    int j = j0 + jj;
    const float* wr = w + (long)j * 768;
    float p = 0.f;
    #pragma unroll
    for (int i = 0; i < 12; i++) p += sv[lane + 64*i] * wr[lane + 64*i];
    for (int o = 32; o; o >>= 1) p += __shfl_xor(p, o);
    if (lane == 0) out[bb*4608 + j] = p + b[j];
  }
}

// ---- y = (1+c)*LN(x) + s ----
__global__ __launch_bounds__(256) void ln_mod_kernel(const float* __restrict__ x,
    const float* __restrict__ mod, bf16* __restrict__ y, int L){
  int t = blockIdx.x; int b = t / L;
  const float* xr = x + (long)t * 768;
  __shared__ float red[256];
  int tid = threadIdx.x;
  float v[3]; float s = 0.f;
  #pragma unroll
  for (int i = 0; i < 3; i++){ v[i] = xr[tid + 256*i]; s += v[i]; }
  red[tid] = s; __syncthreads();
  for (int o = 128; o; o >>= 1){ if (tid < o) red[tid] += red[tid+o]; __syncthreads(); }
  float mean = red[0] * (1.f/768.f); __syncthreads();
  float s2 = 0.f;
  #pragma unroll
  for (int i = 0; i < 3; i++){ float d = v[i]-mean; s2 += d*d; }
  red[tid] = s2; __syncthreads();
  for (int o = 128; o; o >>= 1){ if (tid < o) red[tid] += red[tid+o]; __syncthreads(); }
  float rs = rsqrtf(red[0] * (1.f/768.f) + 1e-6f);
  const float* mb = mod + (long)b * 4608;
  #pragma unroll
  for (int i = 0; i < 3; i++){
    int d = tid + 256*i;
    y[(long)t*768 + d] = f2bf((1.f + mb[768+d]) * ((v[i]-mean)*rs) + mb[d]);
  }
}

// ---- h = x + g1*(pjA+pjB) ; y = (1+c2)*LN(h) + s2 ----
__global__ __launch_bounds__(256) void resid_ln_mod_kernel(const float* __restrict__ x,
    const float* __restrict__ pj, int pjoff, long pjspo, const float* __restrict__ mod,
    float* __restrict__ h, bf16* __restrict__ y, float* __restrict__ yf, int L){
  int t = blockIdx.x; int b = t / L;
  const float* mb = mod + (long)b * 4608;
  const float* xr = x + (long)t * 768;
  long pr = (long)(pjoff + b*1280 + (t % L)) * 768;
  __shared__ float red[256];
  int tid = threadIdx.x;
  float v[3]; float s = 0.f;
  #pragma unroll
  for (int i = 0; i < 3; i++){
    int d = tid + 256*i;
    float pv = pj[pr + d] + pj[pjspo + pr + d];
    float hv = xr[d] + mb[2*768 + d] * pv;
    h[(long)t*768 + d] = hv;
    v[i] = hv; s += hv;
  }
  red[tid] = s; __syncthreads();
  for (int o = 128; o; o >>= 1){ if (tid < o) red[tid] += red[tid+o]; __syncthreads(); }
  float mean = red[0] * (1.f/768.f); __syncthreads();
  float s2 = 0.f;
  #pragma unroll
  for (int i = 0; i < 3; i++){ float d = v[i]-mean; s2 += d*d; }
  red[tid] = s2; __syncthreads();
  for (int o = 128; o; o >>= 1){ if (tid < o) red[tid] += red[tid+o]; __syncthreads(); }
  float rs = rsqrtf(red[0] * (1.f/768.f) + 1e-6f);
  #pragma unroll
  for (int i = 0; i < 3; i++){
    int d = tid + 256*i;
    float val = (1.f + mb[4*768+d]) * ((v[i]-mean)*rs) + mb[3*768+d];
    y[(long)t*768 + d] = f2bf(val);
    yf[(long)t*768 + d] = val;
  }
}

// ---- qkv rows -> RMS-normed Q,K + transposed V ----
__global__ __launch_bounds__(256) void qkv_scatter_kernel(const bf16* __restrict__ qkv,
    const float* __restrict__ qs, const float* __restrict__ ks,
    bf16* __restrict__ Q, bf16* __restrict__ Kb, bf16* __restrict__ Vt,
    int L, int seqoff){
  __shared__ float vt[64][65];
  int bh = blockIdx.y;
  int b = bh / 12, hh = bh % 12;
  int st = blockIdx.x * 64;
  int w = threadIdx.x >> 6, lane = threadIdx.x & 63;
  float qsc = qs[lane], ksc = ks[lane];
  long qkvbase = (long)b * L * 2304;
  long outbase = (long)bh * 1280 * 64;
  #pragma unroll 4
  for (int i = 0; i < 16; i++){
    int r = w*16 + i;
    int t = st + r;
    const bf16* row = qkv + qkvbase + (long)t * 2304;
    float q = bf2f(row[hh*64 + lane]);
    float k = bf2f(row[768 + hh*64 + lane]);
    float v = bf2f(row[1536 + hh*64 + lane]);
    float q2 = q*q, k2 = k*k;
    for (int o = 32; o; o >>= 1){ q2 += __shfl_xor(q2, o); k2 += __shfl_xor(k2, o); }
    q = q * rsqrtf(q2*(1.f/64.f) + 1e-6f) * qsc;
    k = k * rsqrtf(k2*(1.f/64.f) + 1e-6f) * ksc;
    int seq = seqoff + t;
    Q [outbase + (long)seq*64 + lane] = f2bf(q);
    Kb[outbase + (long)seq*64 + lane] = f2bf(k);
    vt[r][lane] = v;
  }
  __syncthreads();
  #pragma unroll 4
  for (int i = 0; i < 16; i++){
    int d = w*16 + i;
    Vt[outbase + (long)d*1280 + seqoff + st + lane] = f2bf(vt[lane][d]);
  }
}

// ---- row softmax over 1280 ----
__global__ __launch_bounds__(256) void softmax_kernel(const bf16* __restrict__ S, bf16* __restrict__ P){
  long r = blockIdx.x;
  const bf16* sr = S + r * 1280;
  __shared__ float buf[1280];
  __shared__ float red[256];
  int tid = threadIdx.x;
  float mx = -1e30f;
  for (int i = tid; i < 1280; i += 256){ float v = bf2f(sr[i]); buf[i] = v; mx = fmaxf(mx, v); }
  red[tid] = mx; __syncthreads();
  for (int o = 128; o; o >>= 1){ if (tid < o) red[tid] = fmaxf(red[tid], red[tid+o]); __syncthreads(); }
  float m = red[0]; __syncthreads();
  float s = 0.f;
  for (int i = tid; i < 1280; i += 256){ float e = expf(buf[i] - m); buf[i] = e; s += e; }
  red[tid] = s; __syncthreads();
  for (int o = 128; o; o >>= 1){ if (tid < o) red[tid] += red[tid+o]; __syncthreads(); }
  float inv = 1.f / red[0];
  bf16* pr = P + r * 1280;
  for (int i = tid; i < 1280; i += 256) pr[i] = f2bf(buf[i] * inv);
}

// ---- router ----
__global__ __launch_bounds__(256) void router_kernel(const float* __restrict__ x2,
    const float* __restrict__ gw, float* __restrict__ tkw, int* __restrict__ tki,
    int* __restrict__ counts, int T){
  int t = blockIdx.x * 4 + (threadIdx.x >> 6);
  int lane = threadIdx.x & 63;
  if (t >= T) return;
  const float* xr = x2 + (long)t * 768;
  float xs[12];
  #pragma unroll
  for (int i = 0; i < 12; i++) xs[i] = xr[lane + 64*i];
  float sc[8];
  #pragma unroll
  for (int e = 0; e < 8; e++){
    const float* gr = gw + e * 768;
    float p = 0.f;
    #pragma unroll
    for (int i = 0; i < 12; i++) p += xs[i] * gr[lane + 64*i];
    for (int o = 32; o; o >>= 1) p += __shfl_xor(p, o);
    sc[e] = p;
  }
  if (lane == 0){
    float m = sc[0];
    for (int e = 1; e < 8; e++) m = fmaxf(m, sc[e]);
    float s = 0.f;
    for (int e = 0; e < 8; e++){ sc[e] = expf(sc[e] - m); s += sc[e]; }
    float inv = 1.f / s;
    for (int e = 0; e < 8; e++) sc[e] *= inv;
    int i0 = 0;
    for (int e = 1; e < 8; e++) if (sc[e] > sc[i0]) i0 = e;
    int i1 = -1;
    for (int e = 0; e < 8; e++){ if (e == i0) continue; if (i1 < 0 || sc[e] > sc[i1]) i1 = e; }
    tkw[t*2] = sc[i0]; tkw[t*2+1] = sc[i1];
    tki[t*2] = i0;     tki[t*2+1] = i1;
    atomicAdd(&counts[i0], 1); atomicAdd(&counts[i1], 1);
  }
}

__global__ __launch_bounds__(256) void scatter_kernel(const int* __restrict__ tki,
    const int* __restrict__ ofs16, int* __restrict__ cur16,
    int* __restrict__ rows16, int* __restrict__ tpos, int T, int tabofs, int rowadd){
  int idx = blockIdx.x * 256 + threadIdx.x;
  if (idx >= T * 2) return;
  int t = idx >> 1;
  int e = tki[idx];
  int pos = atomicAdd(&cur16[tabofs + e], 1);
  int g = ofs16[tabofs + e] + pos;
  rows16[g] = rowadd + t;
  tpos[idx] = g;
}

// ---- out = h + g2 * (w0*(yeA+yeB)[p0] + w1*(yeA+yeB)[p1] + (ysA+ysB)) ----
__global__ __launch_bounds__(256) void combine_kernel(const float* __restrict__ h,
    const float* __restrict__ mod, const float* __restrict__ tkw, const int* __restrict__ tpos,
    const float* __restrict__ ye, long espo, const float* __restrict__ ys, long sspo,
    float* __restrict__ out, int L){
  int t = blockIdx.x; int b = t / L;
  const float* g2 = mod + (long)b * 4608 + 5*768;
  float w0 = tkw[t*2], w1 = tkw[t*2+1];
  long p0 = (long)tpos[t*2] * 768, p1 = (long)tpos[t*2+1] * 768;
  for (int d = threadIdx.x; d < 768; d += 256){
    float e0 = ye[p0+d] + ye[espo+p0+d];
    float e1 = ye[p1+d] + ye[espo+p1+d];
    float sv = ys[(long)t*768+d] + ys[sspo+(long)t*768+d];
    out[(long)t*768 + d] = h[(long)t*768 + d] + g2[d] * (w0*e0 + w1*e1 + sv);
  }
}

// =================================================================================
extern "C" void kernel_launch(void* const* d_in, const int* in_sizes, int n_in,
                              void* d_out, int out_size, void* d_ws, size_t ws_size,
                              hipStream_t stream){
  (void)in_sizes; (void)n_in; (void)out_size;
  const float* fin[33];
  for (int i = 0; i < 33; i++) fin[i] = (const float*)d_in[i];
  float* out_img = (float*)d_out;
  float* out_txt = (float*)d_out + (long)2*1024*768;

  char* ws = (char*)d_ws;
  size_t off = 0, peak = 0;
  auto alloc = [&](size_t n)->char*{
    off = (off + 255) & ~(size_t)255;
    char* p = ws + off; off += n;
    if (off > peak) peak = off;
    return p;
  };

  // persistent
  float *mod_i, *mod_t, *h_i, *h_t, *x2fc, *tkw_i, *tkw_t;
  bf16 *x2c;
  int *tki_i, *tki_t, *cnt16, *ofs16, *cur16, *rows16, *tpos_i, *tpos_t, *tabs;
  float *qb_ws, *pb_ws;
  // weights (tier A)
  bf16 *wq=nullptr,*wp=nullptr,*wg16=nullptr,*wu16=nullptr,*wd16=nullptr,
       *wsg2=nullptr,*wsu2=nullptr,*wsd2=nullptr;
  // phase A
  bf16 *Qb,*Kb,*Vt,*O,*xmc,*qrc,*S,*P;
  float *pjc,*Opart;
  // phase B
  bf16 *h1,*h1s;
  float *ye,*ys;

  auto build = [&](bool W){
    off = 0; peak = 0;
    mod_i=(float*)alloc(2*4608*4);  mod_t=(float*)alloc(2*4608*4);
    h_i  =(float*)alloc((size_t)2048*768*4); h_t=(float*)alloc((size_t)512*768*4);
    x2c  =(bf16*) alloc((size_t)2560*768*2);
    x2fc =(float*)alloc((size_t)2560*768*4);
    tkw_i=(float*)alloc(2048*2*4); tki_i=(int*)alloc(2048*2*4);
    tkw_t=(float*)alloc(512*2*4);  tki_t=(int*)alloc(512*2*4);
    cnt16=(int*)alloc(16*4); ofs16=(int*)alloc(16*4); cur16=(int*)alloc(16*4);
    rows16=(int*)alloc(5120*4);
    tpos_i=(int*)alloc(4096*4); tpos_t=(int*)alloc(1024*4);
    tabs=(int*)alloc(64*4);
    qb_ws=(float*)alloc(2*2304*4); pb_ws=(float*)alloc(2*768*4);
    if (W){
      const size_t EB = (size_t)8*3072*768*2;
      wg16=(bf16*)alloc(2*EB); wu16=(bf16*)alloc(2*EB); wd16=(bf16*)alloc(2*EB);
      wq  =(bf16*)alloc(2*(size_t)2304*768*2);
      wp  =(bf16*)alloc(2*(size_t)768*768*2);
      wsg2=(bf16*)alloc(2*(size_t)1536*768*2);
      wsu2=(bf16*)alloc(2*(size_t)1536*768*2);
      wsd2=(bf16*)alloc(2*(size_t)768*1536*2);
    }
    size_t arena = (off + 255) & ~(size_t)255;
    // phase A region1
    off = arena;
    Qb=(bf16*)alloc((size_t)24*1280*64*2);
    Kb=(bf16*)alloc((size_t)24*1280*64*2);
    Vt=(bf16*)alloc((size_t)24*1280*64*2);
    O =(bf16*)alloc((size_t)2*1280*768*2);
    pjc=(float*)alloc((size_t)2*2560*768*4);
    size_t sub = (off + 255) & ~(size_t)255;
    // region2a: xm/qr (dead after qkv_scatter)
    xmc=(bf16*)alloc((size_t)2560*768*2);
    qrc=(bf16*)alloc((size_t)2560*2304*2);
    // region2b: S/P/Opart per 6-head chunk
    off = sub;
    S=(bf16*)alloc((size_t)6*1280*1280*2);
    P=(bf16*)alloc((size_t)6*1280*1280*2);
    Opart=(float*)alloc((size_t)10*6*1280*64*4);
    // phase B overlays phase A
    off = arena;
    h1 =(bf16*) alloc((size_t)5120*3072*2);
    ye =(float*)alloc((size_t)2*5120*768*4);
    h1s=(bf16*) alloc((size_t)2560*1536*2);
    ys =(float*)alloc((size_t)2*2560*768*4);
  };

  build(true);
  bool W = (peak <= ws_size);
  if (!W) build(false);

  // bias copies (always)
  hipMemcpyAsync(qb_ws,        fin[8],  2304*4, hipMemcpyDeviceToDevice, stream);
  hipMemcpyAsync(qb_ws+2304,   fin[12], 2304*4, hipMemcpyDeviceToDevice, stream);
  hipMemcpyAsync(pb_ws,        fin[14], 768*4,  hipMemcpyDeviceToDevice, stream);
  hipMemcpyAsync(pb_ws+768,    fin[10], 768*4,  hipMemcpyDeviceToDevice, stream);

  if (W){
    auto cv = [&](const float* src, bf16* dst, long n){
      f2b_kernel<<<(unsigned)((n/8 + 255)/256), 256, 0, stream>>>(src, dst, n);
    };
    const long EN = (long)8*3072*768;
    cv(fin[20], wg16, EN);      cv(fin[27], wg16+EN, EN);
    cv(fin[21], wu16, EN);      cv(fin[28], wu16+EN, EN);
    cv(fin[22], wd16, EN);      cv(fin[29], wd16+EN, EN);
    cv(fin[7],  wq, (long)2304*768);   cv(fin[11], wq+(long)2304*768, (long)2304*768);
    cv(fin[13], wp, (long)768*768);    cv(fin[9],  wp+(long)768*768,  (long)768*768);
    cv(fin[23], wsg2, (long)1536*768); cv(fin[30], wsg2+(long)1536*768, (long)1536*768);
    cv(fin[24], wsu2, (long)1536*768); cv(fin[31], wsu2+(long)1536*768, (long)1536*768);
    cv(fin[25], wsd2, (long)768*1536); cv(fin[32], wsd2+(long)768*1536, (long)768*1536);
  }

  init_kernel<<<1, 64, 0, stream>>>(cnt16, tabs);
  mod_kernel<<<dim3(576,2), 256, 0, stream>>>(fin[2], fin[3], fin[4], mod_i);
  mod_kernel<<<dim3(576,2), 256, 0, stream>>>(fin[2], fin[5], fin[6], mod_t);
  ln_mod_kernel<<<2048, 256, 0, stream>>>(fin[0], mod_i, xmc, 1024);
  ln_mod_kernel<<<512,  256, 0, stream>>>(fin[1], mod_t, xmc + (long)2048*768, 256);

  // QKV (combined z=2)
  if (W)
    k_qkv_b<<<dim3(18,16,2), 256, 0, stream>>>(xmc, wq, nullptr, qb_ws, qrc,
        0, 2304, 768, 0, (long)2304*768, 0, 2304, 1, 0, 0, 2304, 1.f, 1, 0,
        nullptr, tabs+2, tabs+0);
  else {
    k_qkv_f<<<dim3(18,16,1), 256, 0, stream>>>(xmc, fin[7], nullptr, qb_ws, qrc,
        0, 2304, 768, 0, 0, 0, 0, 1, 0, 0, 2304, 1.f, 1, 0, nullptr, tabs+2, tabs+0);
    k_qkv_f<<<dim3(18,4,1), 256, 0, stream>>>(xmc, fin[11], nullptr, qb_ws+2304, qrc,
        0, 2304, 768, 0, 0, 0, 0, 1, 0, 0, 2304, 1.f, 1, 0, nullptr, tabs+3, tabs+1);
  }
  qkv_scatter_kernel<<<dim3(16,24), 256, 0, stream>>>(qrc, fin[15], fin[16], Qb, Kb, Vt, 1024, 256);
  qkv_scatter_kernel<<<dim3(4,24),  256, 0, stream>>>(qrc + (long)2048*2304, fin[17], fin[18], Qb, Kb, Vt, 256, 0);

  // attention: 4 chunks of 6 heads
  for (int ch = 0; ch < 4; ch++){
    const bf16* Qc = Qb + (size_t)ch * 6 * 1280 * 64;
    const bf16* Kc = Kb + (size_t)ch * 6 * 1280 * 64;
    const bf16* Vc = Vt + (size_t)ch * 6 * 1280 * 64;
    k_qkt<<<dim3(10,10,6), 256, 0, stream>>>(Qc, Kc, nullptr, nullptr, S,
        1280, 1280, 64, (long)1280*64, (long)1280*64, 0, 0,
        1, (long)1280*1280, 0, 1280, 0.125f, 1, 0, nullptr, nullptr, nullptr);
    softmax_kernel<<<6*1280, 256, 0, stream>>>(S, P);
    k_pv<<<dim3(1,10,60), 256, 0, stream>>>(P, Vc, nullptr, nullptr, Opart,
        1280, 64, 1280, (long)1280*1280, (long)64*1280, 0, 0,
        1, (long)1280*64, 0, 64, 1.f, 10, (long)6*1280*64, nullptr, nullptr, nullptr);
    reduce_o_kernel<<<dim3(80,6), 256, 0, stream>>>(Opart, O, ch);
  }

  // proj (combined z=4, ks=2)
  if (W)
    k_proj_b<<<dim3(6,8,8), 256, 0, stream>>>(O, wp, nullptr, pb_ws, pjc,
        0, 768, 768, 0, (long)768*768, 1, 768, 1, 0, 0, 768, 1.f, 2, (long)2560*768,
        nullptr, tabs+8, tabs+4);
  else {
    k_proj_f<<<dim3(6,2,4), 256, 0, stream>>>(O, fin[13], nullptr, pb_ws, pjc,
        0, 768, 768, 0, 0, 1, 0, 1, 0, 0, 768, 1.f, 2, (long)2560*768,
        nullptr, tabs+8, tabs+4);
    k_proj_f<<<dim3(6,8,4), 256, 0, stream>>>(O, fin[9], nullptr, pb_ws+768, pjc,
        0, 768, 768, 0, 0, 1, 0, 1, 0, 0, 768, 1.f, 2, (long)2560*768,
        nullptr, tabs+10, tabs+6);
  }
  resid_ln_mod_kernel<<<2048, 256, 0, stream>>>(fin[0], pjc, 256, (long)2560*768,
      mod_i, h_i, x2c, x2fc, 1024);
  resid_ln_mod_kernel<<<512, 256, 0, stream>>>(fin[1], pjc, 0, (long)2560*768,
      mod_t, h_t, x2c + (long)2048*768, x2fc + (long)2048*768, 256);

  router_kernel<<<512, 256, 0, stream>>>(x2fc, fin[19], tkw_i, tki_i, cnt16, 2048);
  router_kernel<<<128, 256, 0, stream>>>(x2fc + (long)2048*768, fin[26], tkw_t, tki_t, cnt16+8, 512);
  tables_kernel<<<1, 1, 0, stream>>>(cnt16, ofs16, cur16);
  scatter_kernel<<<16, 256, 0, stream>>>(tki_i, ofs16, cur16, rows16, tpos_i, 2048, 0, 0);
  scatter_kernel<<<4,  256, 0, stream>>>(tki_t, ofs16, cur16, rows16, tpos_t, 512, 8, 2048);

  // expert gate+up fused (z=16) and down (z=16, ks=2)
  if (W){
    k_gu_b<<<dim3(24,16,16), 256, 0, stream>>>(x2c, wg16, wu16, nullptr, h1,
        0, 3072, 768, 0, (long)3072*768, 0, 0, 1, 0, 0, 3072, 1.f, 1, 0,
        rows16, ofs16, cnt16);
    k_down_b<<<dim3(6,16,32), 256, 0, stream>>>(h1, wd16, nullptr, nullptr, ye,
        0, 768, 3072, 0, (long)768*3072, 0, 0, 1, 0, 0, 768, 1.f, 2, (long)5120*768,
        nullptr, ofs16, cnt16);
    k_sgu_b<<<dim3(12,16,2), 256, 0, stream>>>(x2c, wsg2, wsu2, nullptr, h1s,
        0, 1536, 768, 0, (long)1536*768, 0, 0, 1, 0, 0, 1536, 1.f, 1, 0,
        nullptr, tabs+14, tabs+12);
    k_sdown_b<<<dim3(6,16,4), 256, 0, stream>>>(h1s, wsd2, nullptr, nullptr, ys,
        0, 768, 1536, 0, (long)768*1536, 0, 0, 1, 0, 0, 768, 1.f, 2, (long)2560*768,
        nullptr, tabs+14, tabs+12);
  } else {
    k_gu_f<<<dim3(24,16,8), 256, 0, stream>>>(x2c, fin[20], fin[21], nullptr, h1,
        0, 3072, 768, 0, (long)3072*768, 0, 0, 1, 0, 0, 3072, 1.f, 1, 0,
        rows16, ofs16, cnt16);
    k_gu_f<<<dim3(24,16,8), 256, 0, stream>>>(x2c, fin[27], fin[28], nullptr, h1,
        0, 3072, 768, 0, (long)3072*768, 0, 0, 1, 0, 0, 3072, 1.f, 1, 0,
        rows16, ofs16+8, cnt16+8);
    k_down_f<<<dim3(6,16,16), 256, 0, stream>>>(h1, fin[22], nullptr, nullptr, ye,
        0, 768, 3072, 0, (long)768*3072, 0, 0, 1, 0, 0, 768, 1.f, 2, (long)5120*768,
        nullptr, ofs16, cnt16);
    k_down_f<<<dim3(6,16,16), 256, 0, stream>>>(h1, fin[29], nullptr, nullptr, ye,
        0, 768, 3072, 0, (long)768*3072, 0, 0, 1, 0, 0, 768, 1.f, 2, (long)5120*768,
        nullptr, ofs16+8, cnt16+8);
    k_sgu_f<<<dim3(12,16,1), 256, 0, stream>>>(x2c, fin[23], fin[24], nullptr, h1s,
        0, 1536, 768, 0, 0, 0, 0, 1, 0, 0, 1536, 1.f, 1, 0, nullptr, tabs+14, tabs+12);
    k_sgu_f<<<dim3(12,4,1), 256, 0, stream>>>(x2c, fin[30], fin[31], nullptr, h1s,
        0, 1536, 768, 0, 0, 0, 0, 1, 0, 0, 1536, 1.f, 1, 0, nullptr, tabs+15, tabs+13);
    k_sdown_f<<<dim3(6,16,2), 256, 0, stream>>>(h1s, fin[25], nullptr, nullptr, ys,
        0, 768, 1536, 0, 0, 0, 0, 1, 0, 0, 768, 1.f, 2, (long)2560*768,
        nullptr, tabs+14, tabs+12);
    k_sdown_f<<<dim3(6,4,2), 256, 0, stream>>>(h1s, fin[32], nullptr, nullptr, ys,
        0, 768, 1536, 0, 0, 0, 0, 1, 0, 0, 768, 1.f, 2, (long)2560*768,
        nullptr, tabs+15, tabs+13);
  }
  combine_kernel<<<2048, 256, 0, stream>>>(h_i, mod_i, tkw_i, tpos_i,
      ye, (long)5120*768, ys, (long)2560*768, out_img, 1024);
  combine_kernel<<<512, 256, 0, stream>>>(h_t, mod_t, tkw_t, tpos_t,
      ye, (long)5120*768, ys + (long)2048*768, (long)2560*768, out_txt, 256);
}